// Round 12
// baseline (1317.102 us; speedup 1.0000x reference)
//
#include <hip/hip_runtime.h>
#include <math.h>

#define NB 32
#define HW 4096
#define NS 16
#define EDIM 256
#define FFND 1024
#define EPS_LN 1e-5f
#define EPS_ATTN 1e-5f
#define BPB 32            // sub-blocks per batch in bigpass
#define RPB 128           // rows per bigpass block (HW/BPB)
#define TROWS 16          // rows per barrier-tile inside bigpass

__device__ __forceinline__ float sigmoidf_(float x) { return 1.0f / (1.0f + __expf(-x)); }
__device__ __forceinline__ float gelu_(float x) {
    float x3 = x * x * x;
    return 0.5f * x * (1.0f + tanhf(0.7978845608028654f * (x + 0.044715f * x3)));
}

// Sum over the 16-lane DPP row via row_ror rotations — pure VALU pipe (no
// ds_bpermute). All 16 lanes end with the full sum (per-lane add order
// differs; only lane j==0's value is consumed downstream).
__device__ __forceinline__ float rsum16(float v) {
    int x;
    x = __builtin_amdgcn_update_dpp(0, __float_as_int(v), 0x128, 0xF, 0xF, true); // ror:8
    v += __int_as_float(x);
    x = __builtin_amdgcn_update_dpp(0, __float_as_int(v), 0x124, 0xF, 0xF, true); // ror:4
    v += __int_as_float(x);
    x = __builtin_amdgcn_update_dpp(0, __float_as_int(v), 0x122, 0xF, 0xF, true); // ror:2
    v += __int_as_float(x);
    x = __builtin_amdgcn_update_dpp(0, __float_as_int(v), 0x121, 0xF, 0xF, true); // ror:1
    v += __int_as_float(x);
    return v;
}

// W[j][c] = scale * sum_e w_q[e][j] * w_k[e][c]   (scale = 256^-0.5 = 1/16)
__global__ void k_prep(const float* __restrict__ w_q, const float* __restrict__ w_k,
                       float* __restrict__ W) {
    const int j = blockIdx.x;
    const int c = threadIdx.x;
    float acc = 0.f;
    for (int e = 0; e < EDIM; ++e)
        acc += w_q[e * EDIM + j] * w_k[e * EDIM + c];
    W[j * EDIM + c] = acc * 0.0625f;
}

// Tiled transpose: src[R][C] -> dst[C][R].  R,C multiples of 64. 64x64 tiles.
__global__ __launch_bounds__(256) void k_tr(const float* __restrict__ src,
                                            float* __restrict__ dst, int R, int C) {
    __shared__ float tile[64][65];
    const int tilesC = C >> 6;
    const int tR = (blockIdx.x / tilesC) << 6;
    const int tC = (blockIdx.x % tilesC) << 6;
    const int t = threadIdx.x;
    {
        const int r = t >> 2;
        const int c0 = (t & 3) << 4;
#pragma unroll
        for (int i = 0; i < 16; i += 4) {
            const float4 v = *reinterpret_cast<const float4*>(src + (size_t)(tR + r) * C + tC + c0 + i);
            tile[r][c0 + i] = v.x; tile[r][c0 + i + 1] = v.y;
            tile[r][c0 + i + 2] = v.z; tile[r][c0 + i + 3] = v.w;
        }
    }
    __syncthreads();
    {
        const int c = t >> 2;
        const int r0 = (t & 3) << 4;
#pragma unroll
        for (int i = 0; i < 16; ++i)
            dst[(size_t)(tC + c) * R + tR + r0 + i] = tile[r0 + i][c];
    }
}

// Iteration-0 only: qn = LN(query_row); qpk = (qn @ W) * g_kv  (pre-folded G!);
// gq/bq scalars from the raw projection.
__global__ void k_qproj(const float* __restrict__ qsrc, const float* __restrict__ g_q,
                        const float* __restrict__ b_q, const float* __restrict__ W,
                        const float* __restrict__ g_kv, const float* __restrict__ b_kv,
                        float* __restrict__ qpk, float* __restrict__ gqbq) {
    const int row = blockIdx.x;   // 0..511  (= b*16 + s)
    const int t = threadIdx.x;
    __shared__ float qn[EDIM];
    __shared__ float red[16];
    const float v = qsrc[(size_t)row * EDIM + t];
    float s = v, ss = v * v;
#pragma unroll
    for (int m = 1; m < 64; m <<= 1) { s += __shfl_xor(s, m); ss += __shfl_xor(ss, m); }
    const int wave = t >> 6, lane = t & 63;
    if (lane == 0) { red[wave] = s; red[8 + wave] = ss; }
    __syncthreads();
    const float st = red[0] + red[1] + red[2] + red[3];
    const float sst = red[8] + red[9] + red[10] + red[11];
    const float mean = st * (1.0f / EDIM);
    const float rstd = rsqrtf(sst * (1.0f / EDIM) - mean * mean + EPS_LN);
    qn[t] = (v - mean) * rstd * g_q[t] + b_q[t];
    __syncthreads();
    float acc = 0.f;
    for (int j = 0; j < EDIM; ++j)
        acc += qn[j] * W[j * EDIM + t];
    const float gk = g_kv[t];
    qpk[(size_t)row * EDIM + t] = acc * gk;   // store g_kv-folded (Gg)
    float u = acc * gk;
    float w2 = acc * b_kv[t];
#pragma unroll
    for (int m = 1; m < 64; m <<= 1) { u += __shfl_xor(u, m); w2 += __shfl_xor(w2, m); }
    __syncthreads();
    if (lane == 0) { red[wave] = u; red[8 + wave] = w2; }
    __syncthreads();
    if (t == 0) {
        const int b = row >> 4, sl = row & 15;
        gqbq[b * 32 + sl] = red[0] + red[1] + red[2] + red[3];
        gqbq[b * 32 + 16 + sl] = red[8] + red[9] + red[10] + red[11];
    }
}

// Streaming pass v7: LDS holds only the x stage (~18 KB). G (=g_kv*qpk) is read
// from global (16 KB/batch, L1-resident). Row reductions use DPP row_ror adds
// (VALU pipe) instead of __shfl_xor (ds_bpermute = LDS pipe). r10 accounting
// showed the LDS pipe (G ds_reads 768cyc + bpermute 464cyc + phaseB 570cyc per
// wave-tile, x16 waves/CU) was the binding resource at 116us/pass.
template <bool LAST>
__global__ __launch_bounds__(256, 2) void k_bigpass(
    const float* __restrict__ input, const float* __restrict__ qpk,
    const float* __restrict__ gqbq, const float* __restrict__ g_kv,
    float* __restrict__ pacc, float* __restrict__ psum, float* __restrict__ attn_out) {
    const int b = blockIdx.x >> 5;        // /BPB
    const int sub = blockIdx.x & 31;      // %BPB
    const int t = threadIdx.x;
    const int w = t >> 6;
    const int lane = t & 63;
    const int g = t >> 4;      // row in tile (0..15)
    const int j = t & 15;      // channel 16th within row

    __shared__ __align__(16) float stage[TROWS][264];  // 16.9 KB padded
    __shared__ __align__(16) float wrec[TROWS][20];    // attn[16], rstd, rstd*mean
    __shared__ float gqbq_s[2][NS];

    if (t < 32) gqbq_s[t >> 4][t & 15] = gqbq[b * 32 + t];
    __syncthreads();

    const float* __restrict__ Gg = qpk + (size_t)b * 4096;   // g_kv-folded, L1-hot

    float acc[4][4];
    float S[4], A[4];
#pragma unroll
    for (int si = 0; si < 4; ++si) {
        acc[si][0] = acc[si][1] = acc[si][2] = acc[si][3] = 0.f;
        S[si] = 0.f; A[si] = 0.f;
    }

    const int rowbase = sub * RPB;
#pragma unroll 1
    for (int tt = 0; tt < RPB / TROWS; ++tt) {
        const int grow = rowbase + tt * TROWS + g;
        const float* xa = input + ((size_t)b * HW + grow) * EDIM;

        // ---- phase A ----
        float p[NS];
#pragma unroll
        for (int s = 0; s < NS; ++s) p[s] = 0.f;
        float s1 = 0.f, s2 = 0.f;
#pragma unroll
        for (int c = 0; c < 4; ++c) {
            const int off = (c * 16 + j) * 4;
            const float4 x = *reinterpret_cast<const float4*>(xa + off);
            *reinterpret_cast<float4*>(&stage[g][off]) = x;
            s1 += x.x + x.y + x.z + x.w;
            s2 += x.x * x.x + x.y * x.y + x.z * x.z + x.w * x.w;
#pragma unroll
            for (int s = 0; s < NS; ++s) {
                const float4 gg = *reinterpret_cast<const float4*>(Gg + s * EDIM + off);
                p[s] += x.x * gg.x + x.y * gg.y + x.z * gg.z + x.w * gg.w;
            }
        }
        // DPP row reductions (VALU pipe)
        s1 = rsum16(s1);
        s2 = rsum16(s2);
#pragma unroll
        for (int s = 0; s < NS; ++s) p[s] = rsum16(p[s]);

        const float mean = s1 * (1.0f / EDIM);
        const float rstd = rsqrtf(s2 * (1.0f / EDIM) - mean * mean + EPS_LN);
        float mx = -1e30f;
#pragma unroll
        for (int s = 0; s < NS; ++s) {
            p[s] = rstd * (p[s] - mean * gqbq_s[0][s]) + gqbq_s[1][s];
            mx = fmaxf(mx, p[s]);
        }
        float tot = 0.f;
#pragma unroll
        for (int s = 0; s < NS; ++s) { p[s] = __expf(p[s] - mx); tot += p[s]; }
        const float inv = 1.0f / tot;
#pragma unroll
        for (int s = 0; s < NS; ++s) p[s] *= inv;

        if (j == 0) {
#pragma unroll
            for (int sq = 0; sq < 4; ++sq)
                *reinterpret_cast<float4*>(&wrec[g][sq * 4]) =
                    make_float4(p[sq * 4], p[sq * 4 + 1], p[sq * 4 + 2], p[sq * 4 + 3]);
            wrec[g][16] = rstd;
            wrec[g][17] = rstd * mean;
            if (LAST) {
#pragma unroll
                for (int s = 0; s < NS; ++s)
                    attn_out[((size_t)(b * NS + s)) * HW + grow] = p[s];
            }
        }
        __syncthreads();

        // ---- phase B: wave w accumulates slots 4w..4w+3 from staged x ----
        {
            const int ch = lane * 4;
            const int sbase = w * 4;
#pragma unroll
            for (int r = 0; r < TROWS; ++r) {
                const float4 xv = *reinterpret_cast<const float4*>(&stage[r][ch]);
                const float4 at = *reinterpret_cast<const float4*>(&wrec[r][sbase]);
                const float rr = wrec[r][16];
                const float rm = wrec[r][17];
                float wg;
                wg = at.x * rr;
                acc[0][0] += wg * xv.x; acc[0][1] += wg * xv.y;
                acc[0][2] += wg * xv.z; acc[0][3] += wg * xv.w;
                S[0] += at.x; A[0] += at.x * rm;
                wg = at.y * rr;
                acc[1][0] += wg * xv.x; acc[1][1] += wg * xv.y;
                acc[1][2] += wg * xv.z; acc[1][3] += wg * xv.w;
                S[1] += at.y; A[1] += at.y * rm;
                wg = at.z * rr;
                acc[2][0] += wg * xv.x; acc[2][1] += wg * xv.y;
                acc[2][2] += wg * xv.z; acc[2][3] += wg * xv.w;
                S[2] += at.z; A[2] += at.z * rm;
                wg = at.w * rr;
                acc[3][0] += wg * xv.x; acc[3][1] += wg * xv.y;
                acc[3][2] += wg * xv.z; acc[3][3] += wg * xv.w;
                S[3] += at.w; A[3] += at.w * rm;
            }
        }
        __syncthreads();
    }

    // epilogue: each wave writes its own 4 slots
#pragma unroll
    for (int si = 0; si < 4; ++si) {
        *reinterpret_cast<float4*>(
            pacc + ((size_t)blockIdx.x * NS + w * 4 + si) * EDIM + lane * 4) =
            make_float4(acc[si][0], acc[si][1], acc[si][2], acc[si][3]);
    }
    if (lane == 0) {
#pragma unroll
        for (int si = 0; si < 4; ++si) {
            psum[blockIdx.x * 32 + w * 4 + si] = S[si];
            psum[blockIdx.x * 32 + 16 + w * 4 + si] = A[si];
        }
    }
}

// G1: partial reduce + ub + updates = ub @ w_v.T.  grid 256: (rt 0..127) x (ct 0..1)
__global__ __launch_bounds__(256) void k_upd(
    const float* __restrict__ pacc, const float* __restrict__ psum,
    const float* __restrict__ g_kv, const float* __restrict__ b_kv,
    const float* __restrict__ w_vT, float* __restrict__ updates) {
    const int rt = blockIdx.x >> 1;
    const int ct = blockIdx.x & 1;
    const int row0 = rt * 4;
    const int b = row0 >> 4;
    const int s0 = row0 & 15;
    const int t = threadIdx.x;
    __shared__ __align__(16) float ub[4][EDIM];
    __shared__ float sSA[4][2];

    if (t < 8) {
        const int r = t & 3;
        const int isA = t >> 2;
        float v = 0.f;
        for (int p = 0; p < BPB; ++p)
            v += psum[(b * BPB + p) * 32 + isA * 16 + s0 + r];
        sSA[r][isA] = v;
    }
    __syncthreads();
#pragma unroll
    for (int r = 0; r < 4; ++r) {
        float V = 0.f;
        for (int p = 0; p < BPB; ++p)
            V += pacc[((size_t)(b * BPB + p) * NS + s0 + r) * EDIM + t];
        const float Sv = sSA[r][0], Av = sSA[r][1];
        ub[r][t] = (g_kv[t] * (V - Av) + b_kv[t] * Sv) / (Sv + EPS_ATTN);
    }
    __syncthreads();

    const int c = ct * 128 + (t & 127);
    const int half = t >> 7;       // 2 rows per thread
    const float* u0 = ub[2 * half];
    const float* u1 = ub[2 * half + 1];
    float a0 = 0.f, a1 = 0.f;
#pragma unroll 4
    for (int j = 0; j < EDIM; j += 4) {
        const float4 x0 = *reinterpret_cast<const float4*>(u0 + j);
        const float4 x1 = *reinterpret_cast<const float4*>(u1 + j);
        const float w0 = w_vT[(size_t)j * EDIM + c];
        const float w1 = w_vT[(size_t)(j + 1) * EDIM + c];
        const float w2 = w_vT[(size_t)(j + 2) * EDIM + c];
        const float w3 = w_vT[(size_t)(j + 3) * EDIM + c];
        a0 += x0.x * w0 + x0.y * w1 + x0.z * w2 + x0.w * w3;
        a1 += x1.x * w0 + x1.y * w1 + x1.z * w2 + x1.w * w3;
    }
    updates[(size_t)(row0 + 2 * half) * EDIM + c] = a0;
    updates[(size_t)(row0 + 2 * half + 1) * EDIM + c] = a1;
}

// G2a: gi = upd @ w_ih.T + b_ih (ct 0..2), gh = qprev @ w_hh.T + b_hh (ct 3..5).
// grid 768: rt = bid/6 (4 rows), ct = bid%6 (256 cols).
__global__ __launch_bounds__(256) void k_gates(
    const float* __restrict__ updates, const float* __restrict__ qprev,
    const float* __restrict__ w_ihT, const float* __restrict__ w_hhT,
    const float* __restrict__ b_ih, const float* __restrict__ b_hh,
    float* __restrict__ gig) {
    const int rt = blockIdx.x / 6;
    const int ct = blockIdx.x % 6;
    const int row0 = rt * 4;
    const int t = threadIdx.x;
    const bool ih = ct < 3;
    const int lc = (ih ? ct : ct - 3) * 256 + t;   // 0..767
    const float* __restrict__ src = ih ? updates : qprev;
    const float* __restrict__ wT = ih ? w_ihT : w_hhT;

    __shared__ __align__(16) float in4[4][EDIM];
#pragma unroll
    for (int r = 0; r < 4; ++r)
        in4[r][t] = src[(size_t)(row0 + r) * EDIM + t];
    __syncthreads();

    float a0 = 0.f, a1 = 0.f, a2 = 0.f, a3 = 0.f;
#pragma unroll 4
    for (int j = 0; j < EDIM; j += 4) {
        const float4 x0 = *reinterpret_cast<const float4*>(&in4[0][j]);
        const float4 x1 = *reinterpret_cast<const float4*>(&in4[1][j]);
        const float4 x2 = *reinterpret_cast<const float4*>(&in4[2][j]);
        const float4 x3 = *reinterpret_cast<const float4*>(&in4[3][j]);
        const float w0 = wT[(size_t)j * 768 + lc];
        const float w1 = wT[(size_t)(j + 1) * 768 + lc];
        const float w2 = wT[(size_t)(j + 2) * 768 + lc];
        const float w3 = wT[(size_t)(j + 3) * 768 + lc];
        a0 += x0.x * w0 + x0.y * w1 + x0.z * w2 + x0.w * w3;
        a1 += x1.x * w0 + x1.y * w1 + x1.z * w2 + x1.w * w3;
        a2 += x2.x * w0 + x2.y * w1 + x2.z * w2 + x2.w * w3;
        a3 += x3.x * w0 + x3.y * w1 + x3.z * w2 + x3.w * w3;
    }
    const float bias = ih ? b_ih[lc] : b_hh[lc];
    const int gcol = ih ? lc : 768 + lc;
    gig[(size_t)(row0 + 0) * 1536 + gcol] = a0 + bias;
    gig[(size_t)(row0 + 1) * 1536 + gcol] = a1 + bias;
    gig[(size_t)(row0 + 2) * 1536 + gcol] = a2 + bias;
    gig[(size_t)(row0 + 3) * 1536 + gcol] = a3 + bias;
}

// G2b+G3 fused: recompute GRU pointwise + LN for this block's 4 rows, then
// h1 slice = gelu(ln2 @ w_f1T[:, ct*256..+255] + b_f1).
// grid 512: rt = bid>>2 (4 rows), ct = bid&3 (256 cols).
__global__ __launch_bounds__(256) void k_gruffn1(
    const float* __restrict__ gig, const float* __restrict__ qprev,
    const float* __restrict__ g_2, const float* __restrict__ b_2,
    const float* __restrict__ w_f1T, const float* __restrict__ b_f1,
    float* __restrict__ slots, float* __restrict__ h1) {
    const int rt = blockIdx.x >> 2;
    const int ct = blockIdx.x & 3;
    const int row0 = rt * 4;
    const int t = threadIdx.x;
    const int wave = t >> 6, lane = t & 63;
    __shared__ __align__(16) float ln2[4][EDIM];
    __shared__ float red[4][8];

    float sl[4];
#pragma unroll
    for (int r = 0; r < 4; ++r) {
        const size_t base = (size_t)(row0 + r) * 1536;
        const float ir = gig[base + t];
        const float iz = gig[base + 256 + t];
        const float inn = gig[base + 512 + t];
        const float hr = gig[base + 768 + t];
        const float hz = gig[base + 1024 + t];
        const float hn = gig[base + 1280 + t];
        const float h = qprev[(size_t)(row0 + r) * EDIM + t];
        const float rg = sigmoidf_(ir + hr);
        const float z = sigmoidf_(iz + hz);
        const float n = tanhf(inn + rg * hn);
        sl[r] = (1.0f - z) * n + z * h;
    }
    if (ct == 0) {
#pragma unroll
        for (int r = 0; r < 4; ++r)
            slots[(size_t)(row0 + r) * EDIM + t] = sl[r];
    }
    {
        float a[4], qq[4];
#pragma unroll
        for (int r = 0; r < 4; ++r) { a[r] = sl[r]; qq[r] = sl[r] * sl[r]; }
#pragma unroll
        for (int m = 1; m < 64; m <<= 1) {
#pragma unroll
            for (int r = 0; r < 4; ++r) {
                a[r] += __shfl_xor(a[r], m);
                qq[r] += __shfl_xor(qq[r], m);
            }
        }
        if (lane == 0) {
#pragma unroll
            for (int r = 0; r < 4; ++r) { red[wave][r] = a[r]; red[wave][4 + r] = qq[r]; }
        }
    }
    __syncthreads();
    {
        const float g = g_2[t], bb = b_2[t];
#pragma unroll
        for (int r = 0; r < 4; ++r) {
            const float Sv = red[0][r] + red[1][r] + red[2][r] + red[3][r];
            const float Qv = red[0][4 + r] + red[1][4 + r] + red[2][4 + r] + red[3][4 + r];
            const float mn = Sv * (1.0f / EDIM);
            const float rs = rsqrtf(Qv * (1.0f / EDIM) - mn * mn + EPS_LN);
            ln2[r][t] = (sl[r] - mn) * rs * g + bb;
        }
    }
    __syncthreads();

    const int c = ct * 256 + t;
    float a0 = 0.f, a1 = 0.f, a2 = 0.f, a3 = 0.f;
#pragma unroll 4
    for (int j = 0; j < EDIM; j += 4) {
        const float4 x0 = *reinterpret_cast<const float4*>(&ln2[0][j]);
        const float4 x1 = *reinterpret_cast<const float4*>(&ln2[1][j]);
        const float4 x2 = *reinterpret_cast<const float4*>(&ln2[2][j]);
        const float4 x3 = *reinterpret_cast<const float4*>(&ln2[3][j]);
        const float w0 = w_f1T[(size_t)j * FFND + c];
        const float w1 = w_f1T[(size_t)(j + 1) * FFND + c];
        const float w2 = w_f1T[(size_t)(j + 2) * FFND + c];
        const float w3 = w_f1T[(size_t)(j + 3) * FFND + c];
        a0 += x0.x * w0 + x0.y * w1 + x0.z * w2 + x0.w * w3;
        a1 += x1.x * w0 + x1.y * w1 + x1.z * w2 + x1.w * w3;
        a2 += x2.x * w0 + x2.y * w1 + x2.z * w2 + x2.w * w3;
        a3 += x3.x * w0 + x3.y * w1 + x3.z * w2 + x3.w * w3;
    }
    const float bf = b_f1[c];
    h1[(size_t)(row0 + 0) * FFND + c] = gelu_(a0 + bf);
    h1[(size_t)(row0 + 1) * FFND + c] = gelu_(a1 + bf);
    h1[(size_t)(row0 + 2) * FFND + c] = gelu_(a2 + bf);
    h1[(size_t)(row0 + 3) * FFND + c] = gelu_(a3 + bf);
}

// G4+G5 fused: q = slots + h1 @ w_f2.T + b_f2 (+adjust), then (if do_qpk)
// LN(q) @ W (times g_kv -> Gg) and gq/bq scalars.  grid 256 blocks x 2 rows.
__global__ __launch_bounds__(256) void k_ffn2qpk(
    const float* __restrict__ h1, const float* __restrict__ slots,
    const float* __restrict__ w_f2T, const float* __restrict__ b_f2,
    const float* __restrict__ query,
    const float* __restrict__ g_q, const float* __restrict__ b_q,
    const float* __restrict__ W,
    const float* __restrict__ g_kv, const float* __restrict__ b_kv,
    float* __restrict__ q_out, float* __restrict__ qpk, float* __restrict__ gqbq,
    int adjust, int do_qpk) {
    const int row0 = blockIdx.x * 2;
    const int t = threadIdx.x;
    const int wave = t >> 6, lane = t & 63;
    __shared__ __align__(16) float in2[2][FFND];
    __shared__ float red[4][4];
    __shared__ __align__(16) float qn[2][EDIM];

#pragma unroll
    for (int r = 0; r < 2; ++r)
        *reinterpret_cast<float4*>(&in2[r][t * 4]) =
            *reinterpret_cast<const float4*>(h1 + (size_t)(row0 + r) * FFND + t * 4);
    __syncthreads();
    float a0 = 0.f, a1 = 0.f;
#pragma unroll 4
    for (int j = 0; j < FFND; j += 4) {
        const float4 x0 = *reinterpret_cast<const float4*>(&in2[0][j]);
        const float4 x1 = *reinterpret_cast<const float4*>(&in2[1][j]);
        const float w0 = w_f2T[(size_t)j * EDIM + t];
        const float w1 = w_f2T[(size_t)(j + 1) * EDIM + t];
        const float w2 = w_f2T[(size_t)(j + 2) * EDIM + t];
        const float w3 = w_f2T[(size_t)(j + 3) * EDIM + t];
        a0 += x0.x * w0 + x0.y * w1 + x0.z * w2 + x0.w * w3;
        a1 += x1.x * w0 + x1.y * w1 + x1.z * w2 + x1.w * w3;
    }
    const float bf = b_f2[t];
    float v0 = slots[(size_t)row0 * EDIM + t] + a0 + bf;
    float v1 = slots[(size_t)(row0 + 1) * EDIM + t] + a1 + bf;
    if (adjust) {
        const float qq0 = query[(size_t)row0 * EDIM + t];
        const float qq1 = query[(size_t)(row0 + 1) * EDIM + t];
        v0 = (v0 + qq0) - qq0;
        v1 = (v1 + qq1) - qq1;
    }
    q_out[(size_t)row0 * EDIM + t] = v0;
    q_out[(size_t)(row0 + 1) * EDIM + t] = v1;

    if (!do_qpk) return;

    {
        float a0r = v0, q0 = v0 * v0, a1r = v1, q1 = v1 * v1;
#pragma unroll
        for (int m = 1; m < 64; m <<= 1) {
            a0r += __shfl_xor(a0r, m); q0 += __shfl_xor(q0, m);
            a1r += __shfl_xor(a1r, m); q1 += __shfl_xor(q1, m);
        }
        if (lane == 0) { red[wave][0] = a0r; red[wave][1] = q0; red[wave][2] = a1r; red[wave][3] = q1; }
    }
    __syncthreads();
    {
        const float S0 = red[0][0] + red[1][0] + red[2][0] + red[3][0];
        const float Q0 = red[0][1] + red[1][1] + red[2][1] + red[3][1];
        const float S1 = red[0][2] + red[1][2] + red[2][2] + red[3][2];
        const float Q1 = red[0][3] + red[1][3] + red[2][3] + red[3][3];
        const float m0 = S0 * (1.0f / EDIM);
        const float r0 = rsqrtf(Q0 * (1.0f / EDIM) - m0 * m0 + EPS_LN);
        const float m1 = S1 * (1.0f / EDIM);
        const float r1 = rsqrtf(Q1 * (1.0f / EDIM) - m1 * m1 + EPS_LN);
        const float g = g_q[t], bb = b_q[t];
        qn[0][t] = (v0 - m0) * r0 * g + bb;
        qn[1][t] = (v1 - m1) * r1 * g + bb;
    }
    __syncthreads();
    float p0 = 0.f, p1 = 0.f;
#pragma unroll 4
    for (int j = 0; j < EDIM; j += 4) {
        const float4 x0 = *reinterpret_cast<const float4*>(&qn[0][j]);
        const float4 x1 = *reinterpret_cast<const float4*>(&qn[1][j]);
        const float w0 = W[(size_t)j * EDIM + t];
        const float w1 = W[(size_t)(j + 1) * EDIM + t];
        const float w2 = W[(size_t)(j + 2) * EDIM + t];
        const float w3 = W[(size_t)(j + 3) * EDIM + t];
        p0 += x0.x * w0 + x0.y * w1 + x0.z * w2 + x0.w * w3;
        p1 += x1.x * w0 + x1.y * w1 + x1.z * w2 + x1.w * w3;
    }
    {
        const float gk = g_kv[t], bk = b_kv[t];
        qpk[(size_t)row0 * EDIM + t] = p0 * gk;        // store g_kv-folded (Gg)
        qpk[(size_t)(row0 + 1) * EDIM + t] = p1 * gk;
        float u0 = p0 * gk, w0 = p0 * bk, u1 = p1 * gk, w1 = p1 * bk;
#pragma unroll
        for (int m = 1; m < 64; m <<= 1) {
            u0 += __shfl_xor(u0, m); w0 += __shfl_xor(w0, m);
            u1 += __shfl_xor(u1, m); w1 += __shfl_xor(w1, m);
        }
        __syncthreads();
        if (lane == 0) { red[wave][0] = u0; red[wave][1] = w0; red[wave][2] = u1; red[wave][3] = w1; }
        __syncthreads();
        if (t == 0) {
            const int b = row0 >> 4;
            const int sl = row0 & 15;
            gqbq[b * 32 + sl] = red[0][0] + red[1][0] + red[2][0] + red[3][0];
            gqbq[b * 32 + 16 + sl] = red[0][1] + red[1][1] + red[2][1] + red[3][1];
            gqbq[b * 32 + sl + 1] = red[0][2] + red[1][2] + red[2][2] + red[3][2];
            gqbq[b * 32 + 16 + sl + 1] = red[0][3] + red[1][3] + red[2][3] + red[3][3];
        }
    }
}

extern "C" void kernel_launch(void* const* d_in, const int* in_sizes, int n_in,
                              void* d_out, int out_size, void* d_ws, size_t ws_size,
                              hipStream_t stream) {
    const float* input = (const float*)d_in[0];
    const float* query = (const float*)d_in[1];
    const float* g_kv = (const float*)d_in[2];
    const float* b_kv = (const float*)d_in[3];
    const float* w_k = (const float*)d_in[4];
    const float* w_v = (const float*)d_in[5];
    const float* g_q = (const float*)d_in[6];
    const float* b_q = (const float*)d_in[7];
    const float* w_q = (const float*)d_in[8];
    const float* w_ih = (const float*)d_in[9];
    const float* w_hh = (const float*)d_in[10];
    const float* b_ih = (const float*)d_in[11];
    const float* b_hh = (const float*)d_in[12];
    const float* g_2 = (const float*)d_in[13];
    const float* b_2 = (const float*)d_in[14];
    const float* w_f1 = (const float*)d_in[15];
    const float* b_f1 = (const float*)d_in[16];
    const float* w_f2 = (const float*)d_in[17];
    const float* b_f2 = (const float*)d_in[18];

    float* ws = (float*)d_ws;
    float* W = ws;        ws += 65536;
    float* qpk = ws;      ws += 131072;
    float* gqbq = ws;     ws += 1024;
    float* psum = ws;     ws += 32768;
    float* q_ws = ws;     ws += 131072;
    float* updates = ws;  ws += 131072;
    float* slots = ws;    ws += 131072;
    float* w_vT = ws;     ws += 65536;
    float* w_ihT = ws;    ws += 196608;
    float* w_hhT = ws;    ws += 196608;
    float* w_f1T = ws;    ws += 262144;
    float* w_f2T = ws;    ws += 262144;
    float* pacc = ws;     ws += (size_t)NB * BPB * NS * EDIM;   // 16 MB
    float* gig = pacc;                        // 512*1536 overlay (after k_upd)
    float* h1 = pacc + 786432;                // 512*1024 overlay

    float* out_q = (float*)d_out;
    float* out_attn = out_q + (size_t)NB * NS * EDIM;

    k_prep<<<256, 256, 0, stream>>>(w_q, w_k, W);
    k_tr<<<16, 256, 0, stream>>>(w_v, w_vT, 256, 256);
    k_tr<<<48, 256, 0, stream>>>(w_ih, w_ihT, 768, 256);
    k_tr<<<48, 256, 0, stream>>>(w_hh, w_hhT, 768, 256);
    k_tr<<<64, 256, 0, stream>>>(w_f1, w_f1T, 1024, 256);
    k_tr<<<64, 256, 0, stream>>>(w_f2, w_f2T, 256, 1024);
    k_qproj<<<512, 256, 0, stream>>>(query, g_q, b_q, W, g_kv, b_kv, qpk, gqbq);

    const float* qprev[3] = {query, q_ws, q_ws};
    float* qdst[3] = {q_ws, q_ws, out_q};
    const int adj[3] = {0, 1, 0};

    for (int it = 0; it < 3; ++it) {
        const bool last = (it == 2);
        if (last)
            k_bigpass<true><<<NB * BPB, 256, 0, stream>>>(input, qpk, gqbq, g_kv, pacc, psum, out_attn);
        else
            k_bigpass<false><<<NB * BPB, 256, 0, stream>>>(input, qpk, gqbq, g_kv, pacc, psum, nullptr);
        k_upd<<<256, 256, 0, stream>>>(pacc, psum, g_kv, b_kv, w_vT, updates);
        k_gates<<<768, 256, 0, stream>>>(updates, qprev[it], w_ihT, w_hhT, b_ih, b_hh, gig);
        k_gruffn1<<<512, 256, 0, stream>>>(gig, qprev[it], g_2, b_2, w_f1T, b_f1, slots, h1);
        k_ffn2qpk<<<256, 256, 0, stream>>>(h1, slots, w_f2T, b_f2, query, g_q, b_q, W,
                                           g_kv, b_kv, qdst[it], qpk, gqbq,
                                           adj[it], last ? 0 : 1);
    }
}

// Round 15
// 495.661 us; speedup vs baseline: 2.6573x; 2.6573x over previous
//
#include <hip/hip_runtime.h>
#include <math.h>

#define NB 32
#define HW 4096
#define NS 16
#define EDIM 256
#define FFND 1024
#define EPS_LN 1e-5f
#define EPS_ATTN 1e-5f
#define BPB 32            // sub-blocks per batch in bigpass
#define RPB 128           // rows per bigpass block (HW/BPB)
#define TROWS 16          // rows per barrier-tile inside bigpass

__device__ __forceinline__ float sigmoidf_(float x) { return 1.0f / (1.0f + __expf(-x)); }
__device__ __forceinline__ float gelu_(float x) {
    float x3 = x * x * x;
    return 0.5f * x * (1.0f + tanhf(0.7978845608028654f * (x + 0.044715f * x3)));
}

// Sum across the 16-lane DPP row via row_ror rotations — pure VALU pipe (no
// ds_bpermute). All 16 lanes end with the full sum (per-lane add order differs;
// only lane j==0's value is consumed downstream).
__device__ __forceinline__ float rsum16(float v) {
    int x;
    x = __builtin_amdgcn_update_dpp(0, __float_as_int(v), 0x128, 0xF, 0xF, true); // ror:8
    v += __int_as_float(x);
    x = __builtin_amdgcn_update_dpp(0, __float_as_int(v), 0x124, 0xF, 0xF, true); // ror:4
    v += __int_as_float(x);
    x = __builtin_amdgcn_update_dpp(0, __float_as_int(v), 0x122, 0xF, 0xF, true); // ror:2
    v += __int_as_float(x);
    x = __builtin_amdgcn_update_dpp(0, __float_as_int(v), 0x121, 0xF, 0xF, true); // ror:1
    v += __int_as_float(x);
    return v;
}

// W[j][c] = scale * sum_e w_q[e][j] * w_k[e][c]   (scale = 256^-0.5 = 1/16)
__global__ void k_prep(const float* __restrict__ w_q, const float* __restrict__ w_k,
                       float* __restrict__ W) {
    const int j = blockIdx.x;
    const int c = threadIdx.x;
    float acc = 0.f;
    for (int e = 0; e < EDIM; ++e)
        acc += w_q[e * EDIM + j] * w_k[e * EDIM + c];
    W[j * EDIM + c] = acc * 0.0625f;
}

// Tiled transpose: src[R][C] -> dst[C][R].  R,C multiples of 64. 64x64 tiles.
__global__ __launch_bounds__(256) void k_tr(const float* __restrict__ src,
                                            float* __restrict__ dst, int R, int C) {
    __shared__ float tile[64][65];
    const int tilesC = C >> 6;
    const int tR = (blockIdx.x / tilesC) << 6;
    const int tC = (blockIdx.x % tilesC) << 6;
    const int t = threadIdx.x;
    {
        const int r = t >> 2;
        const int c0 = (t & 3) << 4;
#pragma unroll
        for (int i = 0; i < 16; i += 4) {
            const float4 v = *reinterpret_cast<const float4*>(src + (size_t)(tR + r) * C + tC + c0 + i);
            tile[r][c0 + i] = v.x; tile[r][c0 + i + 1] = v.y;
            tile[r][c0 + i + 2] = v.z; tile[r][c0 + i + 3] = v.w;
        }
    }
    __syncthreads();
    {
        const int c = t >> 2;
        const int r0 = (t & 3) << 4;
#pragma unroll
        for (int i = 0; i < 16; ++i)
            dst[(size_t)(tC + c) * R + tR + r0 + i] = tile[r0 + i][c];
    }
}

// Iteration-0 only: qn = LN(query_row); qpk = qn @ W; gq/bq scalars.
__global__ void k_qproj(const float* __restrict__ qsrc, const float* __restrict__ g_q,
                        const float* __restrict__ b_q, const float* __restrict__ W,
                        const float* __restrict__ g_kv, const float* __restrict__ b_kv,
                        float* __restrict__ qpk, float* __restrict__ gqbq) {
    const int row = blockIdx.x;   // 0..511  (= b*16 + s)
    const int t = threadIdx.x;
    __shared__ float qn[EDIM];
    __shared__ float red[16];
    const float v = qsrc[(size_t)row * EDIM + t];
    float s = v, ss = v * v;
#pragma unroll
    for (int m = 1; m < 64; m <<= 1) { s += __shfl_xor(s, m); ss += __shfl_xor(ss, m); }
    const int wave = t >> 6, lane = t & 63;
    if (lane == 0) { red[wave] = s; red[8 + wave] = ss; }
    __syncthreads();
    const float st = red[0] + red[1] + red[2] + red[3];
    const float sst = red[8] + red[9] + red[10] + red[11];
    const float mean = st * (1.0f / EDIM);
    const float rstd = rsqrtf(sst * (1.0f / EDIM) - mean * mean + EPS_LN);
    qn[t] = (v - mean) * rstd * g_q[t] + b_q[t];
    __syncthreads();
    float acc = 0.f;
    for (int j = 0; j < EDIM; ++j)
        acc += qn[j] * W[j * EDIM + t];
    qpk[(size_t)row * EDIM + t] = acc;
    float u = acc * g_kv[t];
    float w2 = acc * b_kv[t];
#pragma unroll
    for (int m = 1; m < 64; m <<= 1) { u += __shfl_xor(u, m); w2 += __shfl_xor(w2, m); }
    __syncthreads();
    if (lane == 0) { red[wave] = u; red[8 + wave] = w2; }
    __syncthreads();
    if (t == 0) {
        const int b = row >> 4, sl = row & 15;
        gqbq[b * 32 + sl] = red[0] + red[1] + red[2] + red[3];
        gqbq[b * 32 + 16 + sl] = red[8] + red[9] + red[10] + red[11];
    }
}

// Streaming pass v6d: identical to the r10-proven v6c (G in LDS, 16-row stage,
// launch_bounds(256,2) -> VGPR~88 no spill), with ONE isolated change: the
// phase-A 16-lane reductions use DPP row_ror adds (VALU pipe) instead of
// __shfl_xor (ds_bpermute = LDS pipe).
template <bool LAST>
__global__ __launch_bounds__(256, 2) void k_bigpass(
    const float* __restrict__ input, const float* __restrict__ qpk,
    const float* __restrict__ gqbq, const float* __restrict__ g_kv,
    float* __restrict__ pacc, float* __restrict__ psum, float* __restrict__ attn_out) {
    const int b = blockIdx.x >> 5;        // /BPB
    const int sub = blockIdx.x & 31;      // %BPB
    const int t = threadIdx.x;
    const int w = t >> 6;
    const int lane = t & 63;
    const int g = t >> 4;      // row in tile (0..15)
    const int j = t & 15;      // channel 16th within row

    __shared__ __align__(16) float G[NS][EDIM];        // 16 KB
    __shared__ __align__(16) float stage[TROWS][264];  // 16.5 KB padded
    __shared__ __align__(16) float wrec[TROWS][20];    // attn[16], rstd, rstd*mean
    __shared__ float gqbq_s[2][NS];

    // prologue: G = g_kv (broadcast over s) * qpk[b]
#pragma unroll
    for (int i = 0; i < 4; ++i) {
        const int idx = i * 1024 + t * 4;
        const float4 qv = *reinterpret_cast<const float4*>(qpk + (size_t)b * 4096 + idx);
        const float4 gv = *reinterpret_cast<const float4*>(g_kv + (idx & 255));
        *reinterpret_cast<float4*>(&G[0][0] + idx) =
            make_float4(qv.x * gv.x, qv.y * gv.y, qv.z * gv.z, qv.w * gv.w);
    }
    if (t < 32) gqbq_s[t >> 4][t & 15] = gqbq[b * 32 + t];
    __syncthreads();

    float acc[4][4];
    float S[4], A[4];
#pragma unroll
    for (int si = 0; si < 4; ++si) {
        acc[si][0] = acc[si][1] = acc[si][2] = acc[si][3] = 0.f;
        S[si] = 0.f; A[si] = 0.f;
    }

    const int rowbase = sub * RPB;
#pragma unroll 1
    for (int tt = 0; tt < RPB / TROWS; ++tt) {
        const int grow = rowbase + tt * TROWS + g;
        const float* xa = input + ((size_t)b * HW + grow) * EDIM;

        // ---- phase A ----
        float p[NS];
#pragma unroll
        for (int s = 0; s < NS; ++s) p[s] = 0.f;
        float s1 = 0.f, s2 = 0.f;
#pragma unroll
        for (int c = 0; c < 4; ++c) {
            const int off = (c * 16 + j) * 4;
            const float4 x = *reinterpret_cast<const float4*>(xa + off);
            *reinterpret_cast<float4*>(&stage[g][off]) = x;
            s1 += x.x + x.y + x.z + x.w;
            s2 += x.x * x.x + x.y * x.y + x.z * x.z + x.w * x.w;
#pragma unroll
            for (int s = 0; s < NS; ++s) {
                const float4 gg = *reinterpret_cast<const float4*>(&G[s][off]);
                p[s] += x.x * gg.x + x.y * gg.y + x.z * gg.z + x.w * gg.w;
            }
        }
        // DPP row reductions (VALU pipe, replaces ds_bpermute shfl butterflies)
        s1 = rsum16(s1);
        s2 = rsum16(s2);
#pragma unroll
        for (int s = 0; s < NS; ++s) p[s] = rsum16(p[s]);

        const float mean = s1 * (1.0f / EDIM);
        const float rstd = rsqrtf(s2 * (1.0f / EDIM) - mean * mean + EPS_LN);
        float mx = -1e30f;
#pragma unroll
        for (int s = 0; s < NS; ++s) {
            p[s] = rstd * (p[s] - mean * gqbq_s[0][s]) + gqbq_s[1][s];
            mx = fmaxf(mx, p[s]);
        }
        float tot = 0.f;
#pragma unroll
        for (int s = 0; s < NS; ++s) { p[s] = __expf(p[s] - mx); tot += p[s]; }
        const float inv = 1.0f / tot;
#pragma unroll
        for (int s = 0; s < NS; ++s) p[s] *= inv;

        if (j == 0) {
#pragma unroll
            for (int sq = 0; sq < 4; ++sq)
                *reinterpret_cast<float4*>(&wrec[g][sq * 4]) =
                    make_float4(p[sq * 4], p[sq * 4 + 1], p[sq * 4 + 2], p[sq * 4 + 3]);
            wrec[g][16] = rstd;
            wrec[g][17] = rstd * mean;
            if (LAST) {
#pragma unroll
                for (int s = 0; s < NS; ++s)
                    attn_out[((size_t)(b * NS + s)) * HW + grow] = p[s];
            }
        }
        __syncthreads();

        // ---- phase B: wave w accumulates slots 4w..4w+3 from staged x ----
        {
            const int ch = lane * 4;
            const int sbase = w * 4;
#pragma unroll
            for (int r = 0; r < TROWS; ++r) {
                const float4 xv = *reinterpret_cast<const float4*>(&stage[r][ch]);
                const float4 at = *reinterpret_cast<const float4*>(&wrec[r][sbase]);
                const float rr = wrec[r][16];
                const float rm = wrec[r][17];
                float wg;
                wg = at.x * rr;
                acc[0][0] += wg * xv.x; acc[0][1] += wg * xv.y;
                acc[0][2] += wg * xv.z; acc[0][3] += wg * xv.w;
                S[0] += at.x; A[0] += at.x * rm;
                wg = at.y * rr;
                acc[1][0] += wg * xv.x; acc[1][1] += wg * xv.y;
                acc[1][2] += wg * xv.z; acc[1][3] += wg * xv.w;
                S[1] += at.y; A[1] += at.y * rm;
                wg = at.z * rr;
                acc[2][0] += wg * xv.x; acc[2][1] += wg * xv.y;
                acc[2][2] += wg * xv.z; acc[2][3] += wg * xv.w;
                S[2] += at.z; A[2] += at.z * rm;
                wg = at.w * rr;
                acc[3][0] += wg * xv.x; acc[3][1] += wg * xv.y;
                acc[3][2] += wg * xv.z; acc[3][3] += wg * xv.w;
                S[3] += at.w; A[3] += at.w * rm;
            }
        }
        __syncthreads();
    }

    // epilogue: each wave writes its own 4 slots
#pragma unroll
    for (int si = 0; si < 4; ++si) {
        *reinterpret_cast<float4*>(
            pacc + ((size_t)blockIdx.x * NS + w * 4 + si) * EDIM + lane * 4) =
            make_float4(acc[si][0], acc[si][1], acc[si][2], acc[si][3]);
    }
    if (lane == 0) {
#pragma unroll
        for (int si = 0; si < 4; ++si) {
            psum[blockIdx.x * 32 + w * 4 + si] = S[si];
            psum[blockIdx.x * 32 + 16 + w * 4 + si] = A[si];
        }
    }
}

// G1: partial reduce + ub + updates = ub @ w_v.T.  grid 256: (rt 0..127) x (ct 0..1)
__global__ __launch_bounds__(256) void k_upd(
    const float* __restrict__ pacc, const float* __restrict__ psum,
    const float* __restrict__ g_kv, const float* __restrict__ b_kv,
    const float* __restrict__ w_vT, float* __restrict__ updates) {
    const int rt = blockIdx.x >> 1;
    const int ct = blockIdx.x & 1;
    const int row0 = rt * 4;
    const int b = row0 >> 4;
    const int s0 = row0 & 15;
    const int t = threadIdx.x;
    __shared__ __align__(16) float ub[4][EDIM];
    __shared__ float sSA[4][2];

    if (t < 8) {
        const int r = t & 3;
        const int isA = t >> 2;
        float v = 0.f;
        for (int p = 0; p < BPB; ++p)
            v += psum[(b * BPB + p) * 32 + isA * 16 + s0 + r];
        sSA[r][isA] = v;
    }
    __syncthreads();
#pragma unroll
    for (int r = 0; r < 4; ++r) {
        float V = 0.f;
        for (int p = 0; p < BPB; ++p)
            V += pacc[((size_t)(b * BPB + p) * NS + s0 + r) * EDIM + t];
        const float Sv = sSA[r][0], Av = sSA[r][1];
        ub[r][t] = (g_kv[t] * (V - Av) + b_kv[t] * Sv) / (Sv + EPS_ATTN);
    }
    __syncthreads();

    const int c = ct * 128 + (t & 127);
    const int half = t >> 7;       // 2 rows per thread
    const float* u0 = ub[2 * half];
    const float* u1 = ub[2 * half + 1];
    float a0 = 0.f, a1 = 0.f;
#pragma unroll 4
    for (int j = 0; j < EDIM; j += 4) {
        const float4 x0 = *reinterpret_cast<const float4*>(u0 + j);
        const float4 x1 = *reinterpret_cast<const float4*>(u1 + j);
        const float w0 = w_vT[(size_t)j * EDIM + c];
        const float w1 = w_vT[(size_t)(j + 1) * EDIM + c];
        const float w2 = w_vT[(size_t)(j + 2) * EDIM + c];
        const float w3 = w_vT[(size_t)(j + 3) * EDIM + c];
        a0 += x0.x * w0 + x0.y * w1 + x0.z * w2 + x0.w * w3;
        a1 += x1.x * w0 + x1.y * w1 + x1.z * w2 + x1.w * w3;
    }
    updates[(size_t)(row0 + 2 * half) * EDIM + c] = a0;
    updates[(size_t)(row0 + 2 * half + 1) * EDIM + c] = a1;
}

// G2a: gi = upd @ w_ih.T + b_ih (ct 0..2), gh = qprev @ w_hh.T + b_hh (ct 3..5).
// grid 768: rt = bid/6 (4 rows), ct = bid%6 (256 cols).
__global__ __launch_bounds__(256) void k_gates(
    const float* __restrict__ updates, const float* __restrict__ qprev,
    const float* __restrict__ w_ihT, const float* __restrict__ w_hhT,
    const float* __restrict__ b_ih, const float* __restrict__ b_hh,
    float* __restrict__ gig) {
    const int rt = blockIdx.x / 6;
    const int ct = blockIdx.x % 6;
    const int row0 = rt * 4;
    const int t = threadIdx.x;
    const bool ih = ct < 3;
    const int lc = (ih ? ct : ct - 3) * 256 + t;   // 0..767
    const float* __restrict__ src = ih ? updates : qprev;
    const float* __restrict__ wT = ih ? w_ihT : w_hhT;

    __shared__ __align__(16) float in4[4][EDIM];
#pragma unroll
    for (int r = 0; r < 4; ++r)
        in4[r][t] = src[(size_t)(row0 + r) * EDIM + t];
    __syncthreads();

    float a0 = 0.f, a1 = 0.f, a2 = 0.f, a3 = 0.f;
#pragma unroll 4
    for (int j = 0; j < EDIM; j += 4) {
        const float4 x0 = *reinterpret_cast<const float4*>(&in4[0][j]);
        const float4 x1 = *reinterpret_cast<const float4*>(&in4[1][j]);
        const float4 x2 = *reinterpret_cast<const float4*>(&in4[2][j]);
        const float4 x3 = *reinterpret_cast<const float4*>(&in4[3][j]);
        const float w0 = wT[(size_t)j * 768 + lc];
        const float w1 = wT[(size_t)(j + 1) * 768 + lc];
        const float w2 = wT[(size_t)(j + 2) * 768 + lc];
        const float w3 = wT[(size_t)(j + 3) * 768 + lc];
        a0 += x0.x * w0 + x0.y * w1 + x0.z * w2 + x0.w * w3;
        a1 += x1.x * w0 + x1.y * w1 + x1.z * w2 + x1.w * w3;
        a2 += x2.x * w0 + x2.y * w1 + x2.z * w2 + x2.w * w3;
        a3 += x3.x * w0 + x3.y * w1 + x3.z * w2 + x3.w * w3;
    }
    const float bias = ih ? b_ih[lc] : b_hh[lc];
    const int gcol = ih ? lc : 768 + lc;
    gig[(size_t)(row0 + 0) * 1536 + gcol] = a0 + bias;
    gig[(size_t)(row0 + 1) * 1536 + gcol] = a1 + bias;
    gig[(size_t)(row0 + 2) * 1536 + gcol] = a2 + bias;
    gig[(size_t)(row0 + 3) * 1536 + gcol] = a3 + bias;
}

// G2b+G3 fused: recompute GRU pointwise + LN for this block's 4 rows, then
// h1 slice = gelu(ln2 @ w_f1T[:, ct*256..+255] + b_f1).
// grid 512: rt = bid>>2 (4 rows), ct = bid&3 (256 cols).
__global__ __launch_bounds__(256) void k_gruffn1(
    const float* __restrict__ gig, const float* __restrict__ qprev,
    const float* __restrict__ g_2, const float* __restrict__ b_2,
    const float* __restrict__ w_f1T, const float* __restrict__ b_f1,
    float* __restrict__ slots, float* __restrict__ h1) {
    const int rt = blockIdx.x >> 2;
    const int ct = blockIdx.x & 3;
    const int row0 = rt * 4;
    const int t = threadIdx.x;
    const int wave = t >> 6, lane = t & 63;
    __shared__ __align__(16) float ln2[4][EDIM];
    __shared__ float red[4][8];

    float sl[4];
#pragma unroll
    for (int r = 0; r < 4; ++r) {
        const size_t base = (size_t)(row0 + r) * 1536;
        const float ir = gig[base + t];
        const float iz = gig[base + 256 + t];
        const float inn = gig[base + 512 + t];
        const float hr = gig[base + 768 + t];
        const float hz = gig[base + 1024 + t];
        const float hn = gig[base + 1280 + t];
        const float h = qprev[(size_t)(row0 + r) * EDIM + t];
        const float rg = sigmoidf_(ir + hr);
        const float z = sigmoidf_(iz + hz);
        const float n = tanhf(inn + rg * hn);
        sl[r] = (1.0f - z) * n + z * h;
    }
    if (ct == 0) {
#pragma unroll
        for (int r = 0; r < 4; ++r)
            slots[(size_t)(row0 + r) * EDIM + t] = sl[r];
    }
    {
        float a[4], qq[4];
#pragma unroll
        for (int r = 0; r < 4; ++r) { a[r] = sl[r]; qq[r] = sl[r] * sl[r]; }
#pragma unroll
        for (int m = 1; m < 64; m <<= 1) {
#pragma unroll
            for (int r = 0; r < 4; ++r) {
                a[r] += __shfl_xor(a[r], m);
                qq[r] += __shfl_xor(qq[r], m);
            }
        }
        if (lane == 0) {
#pragma unroll
            for (int r = 0; r < 4; ++r) { red[wave][r] = a[r]; red[wave][4 + r] = qq[r]; }
        }
    }
    __syncthreads();
    {
        const float g = g_2[t], bb = b_2[t];
#pragma unroll
        for (int r = 0; r < 4; ++r) {
            const float Sv = red[0][r] + red[1][r] + red[2][r] + red[3][r];
            const float Qv = red[0][4 + r] + red[1][4 + r] + red[2][4 + r] + red[3][4 + r];
            const float mn = Sv * (1.0f / EDIM);
            const float rs = rsqrtf(Qv * (1.0f / EDIM) - mn * mn + EPS_LN);
            ln2[r][t] = (sl[r] - mn) * rs * g + bb;
        }
    }
    __syncthreads();

    const int c = ct * 256 + t;
    float a0 = 0.f, a1 = 0.f, a2 = 0.f, a3 = 0.f;
#pragma unroll 4
    for (int j = 0; j < EDIM; j += 4) {
        const float4 x0 = *reinterpret_cast<const float4*>(&ln2[0][j]);
        const float4 x1 = *reinterpret_cast<const float4*>(&ln2[1][j]);
        const float4 x2 = *reinterpret_cast<const float4*>(&ln2[2][j]);
        const float4 x3 = *reinterpret_cast<const float4*>(&ln2[3][j]);
        const float w0 = w_f1T[(size_t)j * FFND + c];
        const float w1 = w_f1T[(size_t)(j + 1) * FFND + c];
        const float w2 = w_f1T[(size_t)(j + 2) * FFND + c];
        const float w3 = w_f1T[(size_t)(j + 3) * FFND + c];
        a0 += x0.x * w0 + x0.y * w1 + x0.z * w2 + x0.w * w3;
        a1 += x1.x * w0 + x1.y * w1 + x1.z * w2 + x1.w * w3;
        a2 += x2.x * w0 + x2.y * w1 + x2.z * w2 + x2.w * w3;
        a3 += x3.x * w0 + x3.y * w1 + x3.z * w2 + x3.w * w3;
    }
    const float bf = b_f1[c];
    h1[(size_t)(row0 + 0) * FFND + c] = gelu_(a0 + bf);
    h1[(size_t)(row0 + 1) * FFND + c] = gelu_(a1 + bf);
    h1[(size_t)(row0 + 2) * FFND + c] = gelu_(a2 + bf);
    h1[(size_t)(row0 + 3) * FFND + c] = gelu_(a3 + bf);
}

// G4+G5 fused: q = slots + h1 @ w_f2.T + b_f2 (+adjust), then (if do_qpk)
// LN(q) @ W and gq/bq scalars.  grid 256 blocks x 2 rows.
__global__ __launch_bounds__(256) void k_ffn2qpk(
    const float* __restrict__ h1, const float* __restrict__ slots,
    const float* __restrict__ w_f2T, const float* __restrict__ b_f2,
    const float* __restrict__ query,
    const float* __restrict__ g_q, const float* __restrict__ b_q,
    const float* __restrict__ W,
    const float* __restrict__ g_kv, const float* __restrict__ b_kv,
    float* __restrict__ q_out, float* __restrict__ qpk, float* __restrict__ gqbq,
    int adjust, int do_qpk) {
    const int row0 = blockIdx.x * 2;
    const int t = threadIdx.x;
    const int wave = t >> 6, lane = t & 63;
    __shared__ __align__(16) float in2[2][FFND];
    __shared__ float red[4][4];
    __shared__ __align__(16) float qn[2][EDIM];

#pragma unroll
    for (int r = 0; r < 2; ++r)
        *reinterpret_cast<float4*>(&in2[r][t * 4]) =
            *reinterpret_cast<const float4*>(h1 + (size_t)(row0 + r) * FFND + t * 4);
    __syncthreads();
    float a0 = 0.f, a1 = 0.f;
#pragma unroll 4
    for (int j = 0; j < FFND; j += 4) {
        const float4 x0 = *reinterpret_cast<const float4*>(&in2[0][j]);
        const float4 x1 = *reinterpret_cast<const float4*>(&in2[1][j]);
        const float w0 = w_f2T[(size_t)j * EDIM + t];
        const float w1 = w_f2T[(size_t)(j + 1) * EDIM + t];
        const float w2 = w_f2T[(size_t)(j + 2) * EDIM + t];
        const float w3 = w_f2T[(size_t)(j + 3) * EDIM + t];
        a0 += x0.x * w0 + x0.y * w1 + x0.z * w2 + x0.w * w3;
        a1 += x1.x * w0 + x1.y * w1 + x1.z * w2 + x1.w * w3;
    }
    const float bf = b_f2[t];
    float v0 = slots[(size_t)row0 * EDIM + t] + a0 + bf;
    float v1 = slots[(size_t)(row0 + 1) * EDIM + t] + a1 + bf;
    if (adjust) {
        const float qq0 = query[(size_t)row0 * EDIM + t];
        const float qq1 = query[(size_t)(row0 + 1) * EDIM + t];
        v0 = (v0 + qq0) - qq0;
        v1 = (v1 + qq1) - qq1;
    }
    q_out[(size_t)row0 * EDIM + t] = v0;
    q_out[(size_t)(row0 + 1) * EDIM + t] = v1;

    if (!do_qpk) return;

    {
        float a0r = v0, q0 = v0 * v0, a1r = v1, q1 = v1 * v1;
#pragma unroll
        for (int m = 1; m < 64; m <<= 1) {
            a0r += __shfl_xor(a0r, m); q0 += __shfl_xor(q0, m);
            a1r += __shfl_xor(a1r, m); q1 += __shfl_xor(q1, m);
        }
        if (lane == 0) { red[wave][0] = a0r; red[wave][1] = q0; red[wave][2] = a1r; red[wave][3] = q1; }
    }
    __syncthreads();
    {
        const float S0 = red[0][0] + red[1][0] + red[2][0] + red[3][0];
        const float Q0 = red[0][1] + red[1][1] + red[2][1] + red[3][1];
        const float S1 = red[0][2] + red[1][2] + red[2][2] + red[3][2];
        const float Q1 = red[0][3] + red[1][3] + red[2][3] + red[3][3];
        const float m0 = S0 * (1.0f / EDIM);
        const float r0 = rsqrtf(Q0 * (1.0f / EDIM) - m0 * m0 + EPS_LN);
        const float m1 = S1 * (1.0f / EDIM);
        const float r1 = rsqrtf(Q1 * (1.0f / EDIM) - m1 * m1 + EPS_LN);
        const float g = g_q[t], bb = b_q[t];
        qn[0][t] = (v0 - m0) * r0 * g + bb;
        qn[1][t] = (v1 - m1) * r1 * g + bb;
    }
    __syncthreads();
    float p0 = 0.f, p1 = 0.f;
#pragma unroll 4
    for (int j = 0; j < EDIM; j += 4) {
        const float4 x0 = *reinterpret_cast<const float4*>(&qn[0][j]);
        const float4 x1 = *reinterpret_cast<const float4*>(&qn[1][j]);
        const float w0 = W[(size_t)j * EDIM + t];
        const float w1 = W[(size_t)(j + 1) * EDIM + t];
        const float w2 = W[(size_t)(j + 2) * EDIM + t];
        const float w3 = W[(size_t)(j + 3) * EDIM + t];
        p0 += x0.x * w0 + x0.y * w1 + x0.z * w2 + x0.w * w3;
        p1 += x1.x * w0 + x1.y * w1 + x1.z * w2 + x1.w * w3;
    }
    qpk[(size_t)row0 * EDIM + t] = p0;
    qpk[(size_t)(row0 + 1) * EDIM + t] = p1;
    {
        const float gk = g_kv[t], bk = b_kv[t];
        float u0 = p0 * gk, w0 = p0 * bk, u1 = p1 * gk, w1 = p1 * bk;
#pragma unroll
        for (int m = 1; m < 64; m <<= 1) {
            u0 += __shfl_xor(u0, m); w0 += __shfl_xor(w0, m);
            u1 += __shfl_xor(u1, m); w1 += __shfl_xor(w1, m);
        }
        __syncthreads();
        if (lane == 0) { red[wave][0] = u0; red[wave][1] = w0; red[wave][2] = u1; red[wave][3] = w1; }
        __syncthreads();
        if (t == 0) {
            const int b = row0 >> 4;
            const int sl = row0 & 15;
            gqbq[b * 32 + sl] = red[0][0] + red[1][0] + red[2][0] + red[3][0];
            gqbq[b * 32 + 16 + sl] = red[0][1] + red[1][1] + red[2][1] + red[3][1];
            gqbq[b * 32 + sl + 1] = red[0][2] + red[1][2] + red[2][2] + red[3][2];
            gqbq[b * 32 + 16 + sl + 1] = red[0][3] + red[1][3] + red[2][3] + red[3][3];
        }
    }
}

extern "C" void kernel_launch(void* const* d_in, const int* in_sizes, int n_in,
                              void* d_out, int out_size, void* d_ws, size_t ws_size,
                              hipStream_t stream) {
    const float* input = (const float*)d_in[0];
    const float* query = (const float*)d_in[1];
    const float* g_kv = (const float*)d_in[2];
    const float* b_kv = (const float*)d_in[3];
    const float* w_k = (const float*)d_in[4];
    const float* w_v = (const float*)d_in[5];
    const float* g_q = (const float*)d_in[6];
    const float* b_q = (const float*)d_in[7];
    const float* w_q = (const float*)d_in[8];
    const float* w_ih = (const float*)d_in[9];
    const float* w_hh = (const float*)d_in[10];
    const float* b_ih = (const float*)d_in[11];
    const float* b_hh = (const float*)d_in[12];
    const float* g_2 = (const float*)d_in[13];
    const float* b_2 = (const float*)d_in[14];
    const float* w_f1 = (const float*)d_in[15];
    const float* b_f1 = (const float*)d_in[16];
    const float* w_f2 = (const float*)d_in[17];
    const float* b_f2 = (const float*)d_in[18];

    float* ws = (float*)d_ws;
    float* W = ws;        ws += 65536;
    float* qpk = ws;      ws += 131072;
    float* gqbq = ws;     ws += 1024;
    float* psum = ws;     ws += 32768;
    float* q_ws = ws;     ws += 131072;
    float* updates = ws;  ws += 131072;
    float* slots = ws;    ws += 131072;
    float* w_vT = ws;     ws += 65536;
    float* w_ihT = ws;    ws += 196608;
    float* w_hhT = ws;    ws += 196608;
    float* w_f1T = ws;    ws += 262144;
    float* w_f2T = ws;    ws += 262144;
    float* pacc = ws;     ws += (size_t)NB * BPB * NS * EDIM;   // 16 MB
    float* gig = pacc;                        // 512*1536 overlay (after k_upd)
    float* h1 = pacc + 786432;                // 512*1024 overlay

    float* out_q = (float*)d_out;
    float* out_attn = out_q + (size_t)NB * NS * EDIM;

    k_prep<<<256, 256, 0, stream>>>(w_q, w_k, W);
    k_tr<<<16, 256, 0, stream>>>(w_v, w_vT, 256, 256);
    k_tr<<<48, 256, 0, stream>>>(w_ih, w_ihT, 768, 256);
    k_tr<<<48, 256, 0, stream>>>(w_hh, w_hhT, 768, 256);
    k_tr<<<64, 256, 0, stream>>>(w_f1, w_f1T, 1024, 256);
    k_tr<<<64, 256, 0, stream>>>(w_f2, w_f2T, 256, 1024);
    k_qproj<<<512, 256, 0, stream>>>(query, g_q, b_q, W, g_kv, b_kv, qpk, gqbq);

    const float* qprev[3] = {query, q_ws, q_ws};
    float* qdst[3] = {q_ws, q_ws, out_q};
    const int adj[3] = {0, 1, 0};

    for (int it = 0; it < 3; ++it) {
        const bool last = (it == 2);
        if (last)
            k_bigpass<true><<<NB * BPB, 256, 0, stream>>>(input, qpk, gqbq, g_kv, pacc, psum, out_attn);
        else
            k_bigpass<false><<<NB * BPB, 256, 0, stream>>>(input, qpk, gqbq, g_kv, pacc, psum, nullptr);
        k_upd<<<256, 256, 0, stream>>>(pacc, psum, g_kv, b_kv, w_vT, updates);
        k_gates<<<768, 256, 0, stream>>>(updates, qprev[it], w_ihT, w_hhT, b_ih, b_hh, gig);
        k_gruffn1<<<512, 256, 0, stream>>>(gig, qprev[it], g_2, b_2, w_f1T, b_f1, slots, h1);
        k_ffn2qpk<<<256, 256, 0, stream>>>(h1, slots, w_f2T, b_f2, query, g_q, b_q, W,
                                           g_kv, b_kv, qdst[it], qpk, gqbq,
                                           adj[it], last ? 0 : 1);
    }
}

// Round 16
// 475.614 us; speedup vs baseline: 2.7693x; 1.0421x over previous
//
#include <hip/hip_runtime.h>
#include <math.h>

#define NB 32
#define HW 4096
#define NS 16
#define EDIM 256
#define FFND 1024
#define EPS_LN 1e-5f
#define EPS_ATTN 1e-5f
#define BPB 32            // sub-blocks per batch in bigpass
#define RPB 128           // rows per bigpass block (HW/BPB)
#define TROWS 16          // rows per barrier-tile inside bigpass

__device__ __forceinline__ float sigmoidf_(float x) { return 1.0f / (1.0f + __expf(-x)); }
__device__ __forceinline__ float gelu_(float x) {
    float x3 = x * x * x;
    return 0.5f * x * (1.0f + tanhf(0.7978845608028654f * (x + 0.044715f * x3)));
}

// Sum across the 16-lane DPP row via row_ror rotations — pure VALU pipe.
__device__ __forceinline__ float rsum16(float v) {
    int x;
    x = __builtin_amdgcn_update_dpp(0, __float_as_int(v), 0x128, 0xF, 0xF, true); // ror:8
    v += __int_as_float(x);
    x = __builtin_amdgcn_update_dpp(0, __float_as_int(v), 0x124, 0xF, 0xF, true); // ror:4
    v += __int_as_float(x);
    x = __builtin_amdgcn_update_dpp(0, __float_as_int(v), 0x122, 0xF, 0xF, true); // ror:2
    v += __int_as_float(x);
    x = __builtin_amdgcn_update_dpp(0, __float_as_int(v), 0x121, 0xF, 0xF, true); // ror:1
    v += __int_as_float(x);
    return v;
}
// Max across the 16-lane DPP row.
__device__ __forceinline__ float rmax16(float v) {
    int x;
    x = __builtin_amdgcn_update_dpp(0, __float_as_int(v), 0x128, 0xF, 0xF, true);
    v = fmaxf(v, __int_as_float(x));
    x = __builtin_amdgcn_update_dpp(0, __float_as_int(v), 0x124, 0xF, 0xF, true);
    v = fmaxf(v, __int_as_float(x));
    x = __builtin_amdgcn_update_dpp(0, __float_as_int(v), 0x122, 0xF, 0xF, true);
    v = fmaxf(v, __int_as_float(x));
    x = __builtin_amdgcn_update_dpp(0, __float_as_int(v), 0x121, 0xF, 0xF, true);
    v = fmaxf(v, __int_as_float(x));
    return v;
}

// W[j][c] = scale * sum_e w_q[e][j] * w_k[e][c]   (scale = 256^-0.5 = 1/16)
__global__ void k_prep(const float* __restrict__ w_q, const float* __restrict__ w_k,
                       float* __restrict__ W) {
    const int j = blockIdx.x;
    const int c = threadIdx.x;
    float acc = 0.f;
    for (int e = 0; e < EDIM; ++e)
        acc += w_q[e * EDIM + j] * w_k[e * EDIM + c];
    W[j * EDIM + c] = acc * 0.0625f;
}

// Tiled transpose: src[R][C] -> dst[C][R].  R,C multiples of 64. 64x64 tiles.
__global__ __launch_bounds__(256) void k_tr(const float* __restrict__ src,
                                            float* __restrict__ dst, int R, int C) {
    __shared__ float tile[64][65];
    const int tilesC = C >> 6;
    const int tR = (blockIdx.x / tilesC) << 6;
    const int tC = (blockIdx.x % tilesC) << 6;
    const int t = threadIdx.x;
    {
        const int r = t >> 2;
        const int c0 = (t & 3) << 4;
#pragma unroll
        for (int i = 0; i < 16; i += 4) {
            const float4 v = *reinterpret_cast<const float4*>(src + (size_t)(tR + r) * C + tC + c0 + i);
            tile[r][c0 + i] = v.x; tile[r][c0 + i + 1] = v.y;
            tile[r][c0 + i + 2] = v.z; tile[r][c0 + i + 3] = v.w;
        }
    }
    __syncthreads();
    {
        const int c = t >> 2;
        const int r0 = (t & 3) << 4;
#pragma unroll
        for (int i = 0; i < 16; ++i)
            dst[(size_t)(tC + c) * R + tR + r0 + i] = tile[r0 + i][c];
    }
}

// Iteration-0 only: qn = LN(query_row); qpk = qn @ W; gq/bq scalars.
__global__ void k_qproj(const float* __restrict__ qsrc, const float* __restrict__ g_q,
                        const float* __restrict__ b_q, const float* __restrict__ W,
                        const float* __restrict__ g_kv, const float* __restrict__ b_kv,
                        float* __restrict__ qpk, float* __restrict__ gqbq) {
    const int row = blockIdx.x;   // 0..511  (= b*16 + s)
    const int t = threadIdx.x;
    __shared__ float qn[EDIM];
    __shared__ float red[16];
    const float v = qsrc[(size_t)row * EDIM + t];
    float s = v, ss = v * v;
#pragma unroll
    for (int m = 1; m < 64; m <<= 1) { s += __shfl_xor(s, m); ss += __shfl_xor(ss, m); }
    const int wave = t >> 6, lane = t & 63;
    if (lane == 0) { red[wave] = s; red[8 + wave] = ss; }
    __syncthreads();
    const float st = red[0] + red[1] + red[2] + red[3];
    const float sst = red[8] + red[9] + red[10] + red[11];
    const float mean = st * (1.0f / EDIM);
    const float rstd = rsqrtf(sst * (1.0f / EDIM) - mean * mean + EPS_LN);
    qn[t] = (v - mean) * rstd * g_q[t] + b_q[t];
    __syncthreads();
    float acc = 0.f;
    for (int j = 0; j < EDIM; ++j)
        acc += qn[j] * W[j * EDIM + t];
    qpk[(size_t)row * EDIM + t] = acc;
    float u = acc * g_kv[t];
    float w2 = acc * b_kv[t];
#pragma unroll
    for (int m = 1; m < 64; m <<= 1) { u += __shfl_xor(u, m); w2 += __shfl_xor(w2, m); }
    __syncthreads();
    if (lane == 0) { red[wave] = u; red[8 + wave] = w2; }
    __syncthreads();
    if (t == 0) {
        const int b = row >> 4, sl = row & 15;
        gqbq[b * 32 + sl] = red[0] + red[1] + red[2] + red[3];
        gqbq[b * 32 + 16 + sl] = red[8] + red[9] + red[10] + red[11];
    }
}

// Streaming pass v8: G held in REGISTERS (wave w owns slots 4w..4w+3; each lane
// holds its 16-channel slice of those 4 slots = 16 float4). Phase A dot is
// slot-split with DPP rsum16 over the 16-lane channel groups — ZERO G LDS
// reads (was 64 ds_read_b128/wave-tile). Logits go through a 1KB logit_lds;
// softmax is lane-per-(row,slot) with DPP max/sum. LDS 34.8->19.2 KB.
template <bool LAST>
__global__ __launch_bounds__(256, 2) void k_bigpass(
    const float* __restrict__ input, const float* __restrict__ qpk,
    const float* __restrict__ gqbq, const float* __restrict__ g_kv,
    float* __restrict__ pacc, float* __restrict__ psum, float* __restrict__ attn_out) {
    const int b = blockIdx.x >> 5;        // /BPB
    const int sub = blockIdx.x & 31;      // %BPB
    const int t = threadIdx.x;
    const int w = t >> 6;        // wave id -> slots 4w..4w+3
    const int lane = t & 63;
    const int gp = (t >> 4) & 3; // row-subgroup within wave (dot phase)
    const int g = t >> 4;        // row 0..15 (staging/softmax)
    const int j = t & 15;        // channel-16th (staging/dot) == slot idx (softmax)

    __shared__ __align__(16) float stage[TROWS][264];   // 16.9 KB padded
    __shared__ __align__(16) float wrec[TROWS][20];     // attn[16], rstd, rstd*mean
    __shared__ __align__(16) float logit_lds[TROWS][NS];

    // per-slot scalars (j = slot index in softmax phase)
    const float gqj = gqbq[b * 32 + j];
    const float bqj = gqbq[b * 32 + 16 + j];

    // G registers: slots 4w..4w+3, this lane's channels j*4+64c (c=0..3)
    float4 Greg[4][4];
#pragma unroll
    for (int sp = 0; sp < 4; ++sp) {
#pragma unroll
        for (int c = 0; c < 4; ++c) {
            const int off = (c * 16 + j) * 4;
            const float4 qv = *reinterpret_cast<const float4*>(
                qpk + (size_t)b * 4096 + (w * 4 + sp) * 256 + off);
            const float4 gv = *reinterpret_cast<const float4*>(g_kv + off);
            Greg[sp][c] = make_float4(qv.x * gv.x, qv.y * gv.y, qv.z * gv.z, qv.w * gv.w);
        }
    }

    float acc[4][4];
    float S[4], A[4];
#pragma unroll
    for (int si = 0; si < 4; ++si) {
        acc[si][0] = acc[si][1] = acc[si][2] = acc[si][3] = 0.f;
        S[si] = 0.f; A[si] = 0.f;
    }

    const int rowbase = sub * RPB;
#pragma unroll 1
    for (int tt = 0; tt < RPB / TROWS; ++tt) {
        const int grow = rowbase + tt * TROWS + g;
        const float* xa = input + ((size_t)b * HW + grow) * EDIM;

        // ---- staging + LN stats (thread owns row g, channels j*4+64c) ----
        float s1 = 0.f, s2 = 0.f;
#pragma unroll
        for (int c = 0; c < 4; ++c) {
            const int off = (c * 16 + j) * 4;
            const float4 x = *reinterpret_cast<const float4*>(xa + off);
            *reinterpret_cast<float4*>(&stage[g][off]) = x;
            s1 += x.x + x.y + x.z + x.w;
            s2 += x.x * x.x + x.y * x.y + x.z * x.z + x.w * x.w;
        }
        s1 = rsum16(s1);
        s2 = rsum16(s2);
        const float mean = s1 * (1.0f / EDIM);
        const float rstd = rsqrtf(s2 * (1.0f / EDIM) - mean * mean + EPS_LN);
        __syncthreads();

        // ---- dot: wave w computes full dots for slots 4w..4w+3 ----
#pragma unroll
        for (int rb = 0; rb < 4; ++rb) {
            const int row = rb * 4 + gp;
            float d0 = 0.f, d1 = 0.f, d2 = 0.f, d3 = 0.f;
#pragma unroll
            for (int c = 0; c < 4; ++c) {
                const int off = (c * 16 + j) * 4;
                const float4 x = *reinterpret_cast<const float4*>(&stage[row][off]);
                d0 += x.x * Greg[0][c].x + x.y * Greg[0][c].y + x.z * Greg[0][c].z + x.w * Greg[0][c].w;
                d1 += x.x * Greg[1][c].x + x.y * Greg[1][c].y + x.z * Greg[1][c].z + x.w * Greg[1][c].w;
                d2 += x.x * Greg[2][c].x + x.y * Greg[2][c].y + x.z * Greg[2][c].z + x.w * Greg[2][c].w;
                d3 += x.x * Greg[3][c].x + x.y * Greg[3][c].y + x.z * Greg[3][c].z + x.w * Greg[3][c].w;
            }
            d0 = rsum16(d0); d1 = rsum16(d1); d2 = rsum16(d2); d3 = rsum16(d3);
            if (j == 0)
                *reinterpret_cast<float4*>(&logit_lds[row][w * 4]) =
                    make_float4(d0, d1, d2, d3);
        }
        __syncthreads();

        // ---- softmax: thread (row g, slot j) ----
        {
            float L = logit_lds[g][j];
            L = rstd * (L - mean * gqj) + bqj;
            const float mx = rmax16(L);
            const float p = __expf(L - mx);
            const float tot = rsum16(p);
            const float at = p / tot;
            wrec[g][j] = at;
            if (j == 0) {
                wrec[g][16] = rstd;
                wrec[g][17] = rstd * mean;
            }
            if (LAST)
                attn_out[((size_t)(b * NS + j)) * HW + grow] = at;
        }
        __syncthreads();

        // ---- phase B: wave w accumulates slots 4w..4w+3 from staged x ----
        {
            const int ch = lane * 4;
            const int sbase = w * 4;
#pragma unroll
            for (int r = 0; r < TROWS; ++r) {
                const float4 xv = *reinterpret_cast<const float4*>(&stage[r][ch]);
                const float4 at = *reinterpret_cast<const float4*>(&wrec[r][sbase]);
                const float rr = wrec[r][16];
                const float rm = wrec[r][17];
                float wg;
                wg = at.x * rr;
                acc[0][0] += wg * xv.x; acc[0][1] += wg * xv.y;
                acc[0][2] += wg * xv.z; acc[0][3] += wg * xv.w;
                S[0] += at.x; A[0] += at.x * rm;
                wg = at.y * rr;
                acc[1][0] += wg * xv.x; acc[1][1] += wg * xv.y;
                acc[1][2] += wg * xv.z; acc[1][3] += wg * xv.w;
                S[1] += at.y; A[1] += at.y * rm;
                wg = at.z * rr;
                acc[2][0] += wg * xv.x; acc[2][1] += wg * xv.y;
                acc[2][2] += wg * xv.z; acc[2][3] += wg * xv.w;
                S[2] += at.z; A[2] += at.z * rm;
                wg = at.w * rr;
                acc[3][0] += wg * xv.x; acc[3][1] += wg * xv.y;
                acc[3][2] += wg * xv.z; acc[3][3] += wg * xv.w;
                S[3] += at.w; A[3] += at.w * rm;
            }
        }
        __syncthreads();
    }

    // epilogue: each wave writes its own 4 slots
#pragma unroll
    for (int si = 0; si < 4; ++si) {
        *reinterpret_cast<float4*>(
            pacc + ((size_t)blockIdx.x * NS + w * 4 + si) * EDIM + lane * 4) =
            make_float4(acc[si][0], acc[si][1], acc[si][2], acc[si][3]);
    }
    if (lane == 0) {
#pragma unroll
        for (int si = 0; si < 4; ++si) {
            psum[blockIdx.x * 32 + w * 4 + si] = S[si];
            psum[blockIdx.x * 32 + 16 + w * 4 + si] = A[si];
        }
    }
}

// G1: partial reduce + ub + updates = ub @ w_v.T.  grid 256: (rt 0..127) x (ct 0..1)
__global__ __launch_bounds__(256) void k_upd(
    const float* __restrict__ pacc, const float* __restrict__ psum,
    const float* __restrict__ g_kv, const float* __restrict__ b_kv,
    const float* __restrict__ w_vT, float* __restrict__ updates) {
    const int rt = blockIdx.x >> 1;
    const int ct = blockIdx.x & 1;
    const int row0 = rt * 4;
    const int b = row0 >> 4;
    const int s0 = row0 & 15;
    const int t = threadIdx.x;
    __shared__ __align__(16) float ub[4][EDIM];
    __shared__ float sSA[4][2];

    if (t < 8) {
        const int r = t & 3;
        const int isA = t >> 2;
        float v = 0.f;
        for (int p = 0; p < BPB; ++p)
            v += psum[(b * BPB + p) * 32 + isA * 16 + s0 + r];
        sSA[r][isA] = v;
    }
    __syncthreads();
#pragma unroll
    for (int r = 0; r < 4; ++r) {
        float V = 0.f;
        for (int p = 0; p < BPB; ++p)
            V += pacc[((size_t)(b * BPB + p) * NS + s0 + r) * EDIM + t];
        const float Sv = sSA[r][0], Av = sSA[r][1];
        ub[r][t] = (g_kv[t] * (V - Av) + b_kv[t] * Sv) / (Sv + EPS_ATTN);
    }
    __syncthreads();

    const int c = ct * 128 + (t & 127);
    const int half = t >> 7;       // 2 rows per thread
    const float* u0 = ub[2 * half];
    const float* u1 = ub[2 * half + 1];
    float a0 = 0.f, a1 = 0.f;
#pragma unroll 4
    for (int j = 0; j < EDIM; j += 4) {
        const float4 x0 = *reinterpret_cast<const float4*>(u0 + j);
        const float4 x1 = *reinterpret_cast<const float4*>(u1 + j);
        const float w0 = w_vT[(size_t)j * EDIM + c];
        const float w1 = w_vT[(size_t)(j + 1) * EDIM + c];
        const float w2 = w_vT[(size_t)(j + 2) * EDIM + c];
        const float w3 = w_vT[(size_t)(j + 3) * EDIM + c];
        a0 += x0.x * w0 + x0.y * w1 + x0.z * w2 + x0.w * w3;
        a1 += x1.x * w0 + x1.y * w1 + x1.z * w2 + x1.w * w3;
    }
    updates[(size_t)(row0 + 2 * half) * EDIM + c] = a0;
    updates[(size_t)(row0 + 2 * half + 1) * EDIM + c] = a1;
}

// G2a: gi = upd @ w_ih.T + b_ih (ct 0..2), gh = qprev @ w_hh.T + b_hh (ct 3..5).
// grid 768: rt = bid/6 (4 rows), ct = bid%6 (256 cols).
__global__ __launch_bounds__(256) void k_gates(
    const float* __restrict__ updates, const float* __restrict__ qprev,
    const float* __restrict__ w_ihT, const float* __restrict__ w_hhT,
    const float* __restrict__ b_ih, const float* __restrict__ b_hh,
    float* __restrict__ gig) {
    const int rt = blockIdx.x / 6;
    const int ct = blockIdx.x % 6;
    const int row0 = rt * 4;
    const int t = threadIdx.x;
    const bool ih = ct < 3;
    const int lc = (ih ? ct : ct - 3) * 256 + t;   // 0..767
    const float* __restrict__ src = ih ? updates : qprev;
    const float* __restrict__ wT = ih ? w_ihT : w_hhT;

    __shared__ __align__(16) float in4[4][EDIM];
#pragma unroll
    for (int r = 0; r < 4; ++r)
        in4[r][t] = src[(size_t)(row0 + r) * EDIM + t];
    __syncthreads();

    float a0 = 0.f, a1 = 0.f, a2 = 0.f, a3 = 0.f;
#pragma unroll 4
    for (int j = 0; j < EDIM; j += 4) {
        const float4 x0 = *reinterpret_cast<const float4*>(&in4[0][j]);
        const float4 x1 = *reinterpret_cast<const float4*>(&in4[1][j]);
        const float4 x2 = *reinterpret_cast<const float4*>(&in4[2][j]);
        const float4 x3 = *reinterpret_cast<const float4*>(&in4[3][j]);
        const float w0 = wT[(size_t)j * 768 + lc];
        const float w1 = wT[(size_t)(j + 1) * 768 + lc];
        const float w2 = wT[(size_t)(j + 2) * 768 + lc];
        const float w3 = wT[(size_t)(j + 3) * 768 + lc];
        a0 += x0.x * w0 + x0.y * w1 + x0.z * w2 + x0.w * w3;
        a1 += x1.x * w0 + x1.y * w1 + x1.z * w2 + x1.w * w3;
        a2 += x2.x * w0 + x2.y * w1 + x2.z * w2 + x2.w * w3;
        a3 += x3.x * w0 + x3.y * w1 + x3.z * w2 + x3.w * w3;
    }
    const float bias = ih ? b_ih[lc] : b_hh[lc];
    const int gcol = ih ? lc : 768 + lc;
    gig[(size_t)(row0 + 0) * 1536 + gcol] = a0 + bias;
    gig[(size_t)(row0 + 1) * 1536 + gcol] = a1 + bias;
    gig[(size_t)(row0 + 2) * 1536 + gcol] = a2 + bias;
    gig[(size_t)(row0 + 3) * 1536 + gcol] = a3 + bias;
}

// G2b+G3 fused: recompute GRU pointwise + LN for this block's 4 rows, then
// h1 slice = gelu(ln2 @ w_f1T[:, ct*256..+255] + b_f1).
// grid 512: rt = bid>>2 (4 rows), ct = bid&3 (256 cols).
__global__ __launch_bounds__(256) void k_gruffn1(
    const float* __restrict__ gig, const float* __restrict__ qprev,
    const float* __restrict__ g_2, const float* __restrict__ b_2,
    const float* __restrict__ w_f1T, const float* __restrict__ b_f1,
    float* __restrict__ slots, float* __restrict__ h1) {
    const int rt = blockIdx.x >> 2;
    const int ct = blockIdx.x & 3;
    const int row0 = rt * 4;
    const int t = threadIdx.x;
    const int wave = t >> 6, lane = t & 63;
    __shared__ __align__(16) float ln2[4][EDIM];
    __shared__ float red[4][8];

    float sl[4];
#pragma unroll
    for (int r = 0; r < 4; ++r) {
        const size_t base = (size_t)(row0 + r) * 1536;
        const float ir = gig[base + t];
        const float iz = gig[base + 256 + t];
        const float inn = gig[base + 512 + t];
        const float hr = gig[base + 768 + t];
        const float hz = gig[base + 1024 + t];
        const float hn = gig[base + 1280 + t];
        const float h = qprev[(size_t)(row0 + r) * EDIM + t];
        const float rg = sigmoidf_(ir + hr);
        const float z = sigmoidf_(iz + hz);
        const float n = tanhf(inn + rg * hn);
        sl[r] = (1.0f - z) * n + z * h;
    }
    if (ct == 0) {
#pragma unroll
        for (int r = 0; r < 4; ++r)
            slots[(size_t)(row0 + r) * EDIM + t] = sl[r];
    }
    {
        float a[4], qq[4];
#pragma unroll
        for (int r = 0; r < 4; ++r) { a[r] = sl[r]; qq[r] = sl[r] * sl[r]; }
#pragma unroll
        for (int m = 1; m < 64; m <<= 1) {
#pragma unroll
            for (int r = 0; r < 4; ++r) {
                a[r] += __shfl_xor(a[r], m);
                qq[r] += __shfl_xor(qq[r], m);
            }
        }
        if (lane == 0) {
#pragma unroll
            for (int r = 0; r < 4; ++r) { red[wave][r] = a[r]; red[wave][4 + r] = qq[r]; }
        }
    }
    __syncthreads();
    {
        const float g = g_2[t], bb = b_2[t];
#pragma unroll
        for (int r = 0; r < 4; ++r) {
            const float Sv = red[0][r] + red[1][r] + red[2][r] + red[3][r];
            const float Qv = red[0][4 + r] + red[1][4 + r] + red[2][4 + r] + red[3][4 + r];
            const float mn = Sv * (1.0f / EDIM);
            const float rs = rsqrtf(Qv * (1.0f / EDIM) - mn * mn + EPS_LN);
            ln2[r][t] = (sl[r] - mn) * rs * g + bb;
        }
    }
    __syncthreads();

    const int c = ct * 256 + t;
    float a0 = 0.f, a1 = 0.f, a2 = 0.f, a3 = 0.f;
#pragma unroll 4
    for (int j = 0; j < EDIM; j += 4) {
        const float4 x0 = *reinterpret_cast<const float4*>(&ln2[0][j]);
        const float4 x1 = *reinterpret_cast<const float4*>(&ln2[1][j]);
        const float4 x2 = *reinterpret_cast<const float4*>(&ln2[2][j]);
        const float4 x3 = *reinterpret_cast<const float4*>(&ln2[3][j]);
        const float w0 = w_f1T[(size_t)j * FFND + c];
        const float w1 = w_f1T[(size_t)(j + 1) * FFND + c];
        const float w2 = w_f1T[(size_t)(j + 2) * FFND + c];
        const float w3 = w_f1T[(size_t)(j + 3) * FFND + c];
        a0 += x0.x * w0 + x0.y * w1 + x0.z * w2 + x0.w * w3;
        a1 += x1.x * w0 + x1.y * w1 + x1.z * w2 + x1.w * w3;
        a2 += x2.x * w0 + x2.y * w1 + x2.z * w2 + x2.w * w3;
        a3 += x3.x * w0 + x3.y * w1 + x3.z * w2 + x3.w * w3;
    }
    const float bf = b_f1[c];
    h1[(size_t)(row0 + 0) * FFND + c] = gelu_(a0 + bf);
    h1[(size_t)(row0 + 1) * FFND + c] = gelu_(a1 + bf);
    h1[(size_t)(row0 + 2) * FFND + c] = gelu_(a2 + bf);
    h1[(size_t)(row0 + 3) * FFND + c] = gelu_(a3 + bf);
}

// G4+G5 fused: q = slots + h1 @ w_f2.T + b_f2 (+adjust), then (if do_qpk)
// LN(q) @ W and gq/bq scalars.  grid 256 blocks x 2 rows.
__global__ __launch_bounds__(256) void k_ffn2qpk(
    const float* __restrict__ h1, const float* __restrict__ slots,
    const float* __restrict__ w_f2T, const float* __restrict__ b_f2,
    const float* __restrict__ query,
    const float* __restrict__ g_q, const float* __restrict__ b_q,
    const float* __restrict__ W,
    const float* __restrict__ g_kv, const float* __restrict__ b_kv,
    float* __restrict__ q_out, float* __restrict__ qpk, float* __restrict__ gqbq,
    int adjust, int do_qpk) {
    const int row0 = blockIdx.x * 2;
    const int t = threadIdx.x;
    const int wave = t >> 6, lane = t & 63;
    __shared__ __align__(16) float in2[2][FFND];
    __shared__ float red[4][4];
    __shared__ __align__(16) float qn[2][EDIM];

#pragma unroll
    for (int r = 0; r < 2; ++r)
        *reinterpret_cast<float4*>(&in2[r][t * 4]) =
            *reinterpret_cast<const float4*>(h1 + (size_t)(row0 + r) * FFND + t * 4);
    __syncthreads();
    float a0 = 0.f, a1 = 0.f;
#pragma unroll 4
    for (int j = 0; j < FFND; j += 4) {
        const float4 x0 = *reinterpret_cast<const float4*>(&in2[0][j]);
        const float4 x1 = *reinterpret_cast<const float4*>(&in2[1][j]);
        const float w0 = w_f2T[(size_t)j * EDIM + t];
        const float w1 = w_f2T[(size_t)(j + 1) * EDIM + t];
        const float w2 = w_f2T[(size_t)(j + 2) * EDIM + t];
        const float w3 = w_f2T[(size_t)(j + 3) * EDIM + t];
        a0 += x0.x * w0 + x0.y * w1 + x0.z * w2 + x0.w * w3;
        a1 += x1.x * w0 + x1.y * w1 + x1.z * w2 + x1.w * w3;
    }
    const float bf = b_f2[t];
    float v0 = slots[(size_t)row0 * EDIM + t] + a0 + bf;
    float v1 = slots[(size_t)(row0 + 1) * EDIM + t] + a1 + bf;
    if (adjust) {
        const float qq0 = query[(size_t)row0 * EDIM + t];
        const float qq1 = query[(size_t)(row0 + 1) * EDIM + t];
        v0 = (v0 + qq0) - qq0;
        v1 = (v1 + qq1) - qq1;
    }
    q_out[(size_t)row0 * EDIM + t] = v0;
    q_out[(size_t)(row0 + 1) * EDIM + t] = v1;

    if (!do_qpk) return;

    {
        float a0r = v0, q0 = v0 * v0, a1r = v1, q1 = v1 * v1;
#pragma unroll
        for (int m = 1; m < 64; m <<= 1) {
            a0r += __shfl_xor(a0r, m); q0 += __shfl_xor(q0, m);
            a1r += __shfl_xor(a1r, m); q1 += __shfl_xor(q1, m);
        }
        if (lane == 0) { red[wave][0] = a0r; red[wave][1] = q0; red[wave][2] = a1r; red[wave][3] = q1; }
    }
    __syncthreads();
    {
        const float S0 = red[0][0] + red[1][0] + red[2][0] + red[3][0];
        const float Q0 = red[0][1] + red[1][1] + red[2][1] + red[3][1];
        const float S1 = red[0][2] + red[1][2] + red[2][2] + red[3][2];
        const float Q1 = red[0][3] + red[1][3] + red[2][3] + red[3][3];
        const float m0 = S0 * (1.0f / EDIM);
        const float r0 = rsqrtf(Q0 * (1.0f / EDIM) - m0 * m0 + EPS_LN);
        const float m1 = S1 * (1.0f / EDIM);
        const float r1 = rsqrtf(Q1 * (1.0f / EDIM) - m1 * m1 + EPS_LN);
        const float g = g_q[t], bb = b_q[t];
        qn[0][t] = (v0 - m0) * r0 * g + bb;
        qn[1][t] = (v1 - m1) * r1 * g + bb;
    }
    __syncthreads();
    float p0 = 0.f, p1 = 0.f;
#pragma unroll 4
    for (int j = 0; j < EDIM; j += 4) {
        const float4 x0 = *reinterpret_cast<const float4*>(&qn[0][j]);
        const float4 x1 = *reinterpret_cast<const float4*>(&qn[1][j]);
        const float w0 = W[(size_t)j * EDIM + t];
        const float w1 = W[(size_t)(j + 1) * EDIM + t];
        const float w2 = W[(size_t)(j + 2) * EDIM + t];
        const float w3 = W[(size_t)(j + 3) * EDIM + t];
        p0 += x0.x * w0 + x0.y * w1 + x0.z * w2 + x0.w * w3;
        p1 += x1.x * w0 + x1.y * w1 + x1.z * w2 + x1.w * w3;
    }
    qpk[(size_t)row0 * EDIM + t] = p0;
    qpk[(size_t)(row0 + 1) * EDIM + t] = p1;
    {
        const float gk = g_kv[t], bk = b_kv[t];
        float u0 = p0 * gk, w0 = p0 * bk, u1 = p1 * gk, w1 = p1 * bk;
#pragma unroll
        for (int m = 1; m < 64; m <<= 1) {
            u0 += __shfl_xor(u0, m); w0 += __shfl_xor(w0, m);
            u1 += __shfl_xor(u1, m); w1 += __shfl_xor(w1, m);
        }
        __syncthreads();
        if (lane == 0) { red[wave][0] = u0; red[wave][1] = w0; red[wave][2] = u1; red[wave][3] = w1; }
        __syncthreads();
        if (t == 0) {
            const int b = row0 >> 4;
            const int sl = row0 & 15;
            gqbq[b * 32 + sl] = red[0][0] + red[1][0] + red[2][0] + red[3][0];
            gqbq[b * 32 + 16 + sl] = red[0][1] + red[1][1] + red[2][1] + red[3][1];
            gqbq[b * 32 + sl + 1] = red[0][2] + red[1][2] + red[2][2] + red[3][2];
            gqbq[b * 32 + 16 + sl + 1] = red[0][3] + red[1][3] + red[2][3] + red[3][3];
        }
    }
}

extern "C" void kernel_launch(void* const* d_in, const int* in_sizes, int n_in,
                              void* d_out, int out_size, void* d_ws, size_t ws_size,
                              hipStream_t stream) {
    const float* input = (const float*)d_in[0];
    const float* query = (const float*)d_in[1];
    const float* g_kv = (const float*)d_in[2];
    const float* b_kv = (const float*)d_in[3];
    const float* w_k = (const float*)d_in[4];
    const float* w_v = (const float*)d_in[5];
    const float* g_q = (const float*)d_in[6];
    const float* b_q = (const float*)d_in[7];
    const float* w_q = (const float*)d_in[8];
    const float* w_ih = (const float*)d_in[9];
    const float* w_hh = (const float*)d_in[10];
    const float* b_ih = (const float*)d_in[11];
    const float* b_hh = (const float*)d_in[12];
    const float* g_2 = (const float*)d_in[13];
    const float* b_2 = (const float*)d_in[14];
    const float* w_f1 = (const float*)d_in[15];
    const float* b_f1 = (const float*)d_in[16];
    const float* w_f2 = (const float*)d_in[17];
    const float* b_f2 = (const float*)d_in[18];

    float* ws = (float*)d_ws;
    float* W = ws;        ws += 65536;
    float* qpk = ws;      ws += 131072;
    float* gqbq = ws;     ws += 1024;
    float* psum = ws;     ws += 32768;
    float* q_ws = ws;     ws += 131072;
    float* updates = ws;  ws += 131072;
    float* slots = ws;    ws += 131072;
    float* w_vT = ws;     ws += 65536;
    float* w_ihT = ws;    ws += 196608;
    float* w_hhT = ws;    ws += 196608;
    float* w_f1T = ws;    ws += 262144;
    float* w_f2T = ws;    ws += 262144;
    float* pacc = ws;     ws += (size_t)NB * BPB * NS * EDIM;   // 16 MB
    float* gig = pacc;                        // 512*1536 overlay (after k_upd)
    float* h1 = pacc + 786432;                // 512*1024 overlay

    float* out_q = (float*)d_out;
    float* out_attn = out_q + (size_t)NB * NS * EDIM;

    k_prep<<<256, 256, 0, stream>>>(w_q, w_k, W);
    k_tr<<<16, 256, 0, stream>>>(w_v, w_vT, 256, 256);
    k_tr<<<48, 256, 0, stream>>>(w_ih, w_ihT, 768, 256);
    k_tr<<<48, 256, 0, stream>>>(w_hh, w_hhT, 768, 256);
    k_tr<<<64, 256, 0, stream>>>(w_f1, w_f1T, 1024, 256);
    k_tr<<<64, 256, 0, stream>>>(w_f2, w_f2T, 256, 1024);
    k_qproj<<<512, 256, 0, stream>>>(query, g_q, b_q, W, g_kv, b_kv, qpk, gqbq);

    const float* qprev[3] = {query, q_ws, q_ws};
    float* qdst[3] = {q_ws, q_ws, out_q};
    const int adj[3] = {0, 1, 0};

    for (int it = 0; it < 3; ++it) {
        const bool last = (it == 2);
        if (last)
            k_bigpass<true><<<NB * BPB, 256, 0, stream>>>(input, qpk, gqbq, g_kv, pacc, psum, out_attn);
        else
            k_bigpass<false><<<NB * BPB, 256, 0, stream>>>(input, qpk, gqbq, g_kv, pacc, psum, nullptr);
        k_upd<<<256, 256, 0, stream>>>(pacc, psum, g_kv, b_kv, w_vT, updates);
        k_gates<<<768, 256, 0, stream>>>(updates, qprev[it], w_ihT, w_hhT, b_ih, b_hh, gig);
        k_gruffn1<<<512, 256, 0, stream>>>(gig, qprev[it], g_2, b_2, w_f1T, b_f1, slots, h1);
        k_ffn2qpk<<<256, 256, 0, stream>>>(h1, slots, w_f2T, b_f2, query, g_q, b_q, W,
                                           g_kv, b_kv, qdst[it], qpk, gqbq,
                                           adj[it], last ? 0 : 1);
    }
}

// Round 17
// 471.242 us; speedup vs baseline: 2.7950x; 1.0093x over previous
//
#include <hip/hip_runtime.h>
#include <math.h>

#define NB 32
#define HW 4096
#define NS 16
#define EDIM 256
#define FFND 1024
#define EPS_LN 1e-5f
#define EPS_ATTN 1e-5f
#define BPB 32            // sub-blocks per batch in bigpass
#define RPB 128           // rows per bigpass block (HW/BPB)
#define TROWS 32          // rows per barrier-tile inside bigpass (v9: 16->32, halves barriers)

__device__ __forceinline__ float sigmoidf_(float x) { return 1.0f / (1.0f + __expf(-x)); }
__device__ __forceinline__ float gelu_(float x) {
    float x3 = x * x * x;
    return 0.5f * x * (1.0f + tanhf(0.7978845608028654f * (x + 0.044715f * x3)));
}

// Sum across the 16-lane DPP row via row_ror rotations — pure VALU pipe.
__device__ __forceinline__ float rsum16(float v) {
    int x;
    x = __builtin_amdgcn_update_dpp(0, __float_as_int(v), 0x128, 0xF, 0xF, true); // ror:8
    v += __int_as_float(x);
    x = __builtin_amdgcn_update_dpp(0, __float_as_int(v), 0x124, 0xF, 0xF, true); // ror:4
    v += __int_as_float(x);
    x = __builtin_amdgcn_update_dpp(0, __float_as_int(v), 0x122, 0xF, 0xF, true); // ror:2
    v += __int_as_float(x);
    x = __builtin_amdgcn_update_dpp(0, __float_as_int(v), 0x121, 0xF, 0xF, true); // ror:1
    v += __int_as_float(x);
    return v;
}
// Max across the 16-lane DPP row.
__device__ __forceinline__ float rmax16(float v) {
    int x;
    x = __builtin_amdgcn_update_dpp(0, __float_as_int(v), 0x128, 0xF, 0xF, true);
    v = fmaxf(v, __int_as_float(x));
    x = __builtin_amdgcn_update_dpp(0, __float_as_int(v), 0x124, 0xF, 0xF, true);
    v = fmaxf(v, __int_as_float(x));
    x = __builtin_amdgcn_update_dpp(0, __float_as_int(v), 0x122, 0xF, 0xF, true);
    v = fmaxf(v, __int_as_float(x));
    x = __builtin_amdgcn_update_dpp(0, __float_as_int(v), 0x121, 0xF, 0xF, true);
    v = fmaxf(v, __int_as_float(x));
    return v;
}

// W[j][c] = scale * sum_e w_q[e][j] * w_k[e][c]   (scale = 256^-0.5 = 1/16)
__global__ void k_prep(const float* __restrict__ w_q, const float* __restrict__ w_k,
                       float* __restrict__ W) {
    const int j = blockIdx.x;
    const int c = threadIdx.x;
    float acc = 0.f;
    for (int e = 0; e < EDIM; ++e)
        acc += w_q[e * EDIM + j] * w_k[e * EDIM + c];
    W[j * EDIM + c] = acc * 0.0625f;
}

// Tiled transpose: src[R][C] -> dst[C][R].  R,C multiples of 64. 64x64 tiles.
__global__ __launch_bounds__(256) void k_tr(const float* __restrict__ src,
                                            float* __restrict__ dst, int R, int C) {
    __shared__ float tile[64][65];
    const int tilesC = C >> 6;
    const int tR = (blockIdx.x / tilesC) << 6;
    const int tC = (blockIdx.x % tilesC) << 6;
    const int t = threadIdx.x;
    {
        const int r = t >> 2;
        const int c0 = (t & 3) << 4;
#pragma unroll
        for (int i = 0; i < 16; i += 4) {
            const float4 v = *reinterpret_cast<const float4*>(src + (size_t)(tR + r) * C + tC + c0 + i);
            tile[r][c0 + i] = v.x; tile[r][c0 + i + 1] = v.y;
            tile[r][c0 + i + 2] = v.z; tile[r][c0 + i + 3] = v.w;
        }
    }
    __syncthreads();
    {
        const int c = t >> 2;
        const int r0 = (t & 3) << 4;
#pragma unroll
        for (int i = 0; i < 16; ++i)
            dst[(size_t)(tC + c) * R + tR + r0 + i] = tile[r0 + i][c];
    }
}

// Iteration-0 only: qn = LN(query_row); qpk = qn @ W; gq/bq scalars.
__global__ void k_qproj(const float* __restrict__ qsrc, const float* __restrict__ g_q,
                        const float* __restrict__ b_q, const float* __restrict__ W,
                        const float* __restrict__ g_kv, const float* __restrict__ b_kv,
                        float* __restrict__ qpk, float* __restrict__ gqbq) {
    const int row = blockIdx.x;   // 0..511  (= b*16 + s)
    const int t = threadIdx.x;
    __shared__ float qn[EDIM];
    __shared__ float red[16];
    const float v = qsrc[(size_t)row * EDIM + t];
    float s = v, ss = v * v;
#pragma unroll
    for (int m = 1; m < 64; m <<= 1) { s += __shfl_xor(s, m); ss += __shfl_xor(ss, m); }
    const int wave = t >> 6, lane = t & 63;
    if (lane == 0) { red[wave] = s; red[8 + wave] = ss; }
    __syncthreads();
    const float st = red[0] + red[1] + red[2] + red[3];
    const float sst = red[8] + red[9] + red[10] + red[11];
    const float mean = st * (1.0f / EDIM);
    const float rstd = rsqrtf(sst * (1.0f / EDIM) - mean * mean + EPS_LN);
    qn[t] = (v - mean) * rstd * g_q[t] + b_q[t];
    __syncthreads();
    float acc = 0.f;
    for (int j = 0; j < EDIM; ++j)
        acc += qn[j] * W[j * EDIM + t];
    qpk[(size_t)row * EDIM + t] = acc;
    float u = acc * g_kv[t];
    float w2 = acc * b_kv[t];
#pragma unroll
    for (int m = 1; m < 64; m <<= 1) { u += __shfl_xor(u, m); w2 += __shfl_xor(w2, m); }
    __syncthreads();
    if (lane == 0) { red[wave] = u; red[8 + wave] = w2; }
    __syncthreads();
    if (t == 0) {
        const int b = row >> 4, sl = row & 15;
        gqbq[b * 32 + sl] = red[0] + red[1] + red[2] + red[3];
        gqbq[b * 32 + 16 + sl] = red[8] + red[9] + red[10] + red[11];
    }
}

// Streaming pass v9: v8 (G in registers, slot-split dot, DPP reductions) with
// TROWS 16->32 — 4 barrier-tiles per pass instead of 8 (16 __syncthreads vs 32).
// r16 accounting showed neither VALU (~1800cyc) nor LDS (~2200cyc) pipe
// saturated against 6900cyc/tile -> barrier-drain bound. LDS 38.3 KB (4 blk/CU).
template <bool LAST>
__global__ __launch_bounds__(256, 2) void k_bigpass(
    const float* __restrict__ input, const float* __restrict__ qpk,
    const float* __restrict__ gqbq, const float* __restrict__ g_kv,
    float* __restrict__ pacc, float* __restrict__ psum, float* __restrict__ attn_out) {
    const int b = blockIdx.x >> 5;        // /BPB
    const int sub = blockIdx.x & 31;      // %BPB
    const int t = threadIdx.x;
    const int w = t >> 6;        // wave id -> slots 4w..4w+3
    const int lane = t & 63;
    const int gp = (t >> 4) & 3; // row-subgroup within wave (dot phase)
    const int g = t >> 4;        // row-pair base 0..15 (staging/softmax: rows g, g+16)
    const int j = t & 15;        // channel-16th (staging/dot) == slot idx (softmax)

    __shared__ __align__(16) float stage[TROWS][264];   // 33.8 KB padded
    __shared__ __align__(16) float wrec[TROWS][20];     // attn[16], rstd, rstd*mean
    __shared__ __align__(16) float logit_lds[TROWS][NS];

    // per-slot scalars (j = slot index in softmax phase)
    const float gqj = gqbq[b * 32 + j];
    const float bqj = gqbq[b * 32 + 16 + j];

    // G registers: slots 4w..4w+3, this lane's channels j*4+64c (c=0..3)
    float4 Greg[4][4];
#pragma unroll
    for (int sp = 0; sp < 4; ++sp) {
#pragma unroll
        for (int c = 0; c < 4; ++c) {
            const int off = (c * 16 + j) * 4;
            const float4 qv = *reinterpret_cast<const float4*>(
                qpk + (size_t)b * 4096 + (w * 4 + sp) * 256 + off);
            const float4 gv = *reinterpret_cast<const float4*>(g_kv + off);
            Greg[sp][c] = make_float4(qv.x * gv.x, qv.y * gv.y, qv.z * gv.z, qv.w * gv.w);
        }
    }

    float acc[4][4];
    float S[4], A[4];
#pragma unroll
    for (int si = 0; si < 4; ++si) {
        acc[si][0] = acc[si][1] = acc[si][2] = acc[si][3] = 0.f;
        S[si] = 0.f; A[si] = 0.f;
    }

    const int rowbase = sub * RPB;
#pragma unroll 1
    for (int tt = 0; tt < RPB / TROWS; ++tt) {
        const int trow0 = rowbase + tt * TROWS;

        // ---- staging + LN stats: thread owns rows g and g+16 ----
        float mean_r[2], rstd_r[2];
#pragma unroll
        for (int rr = 0; rr < 2; ++rr) {
            const int lrow = g + rr * 16;
            const float* xa = input + ((size_t)b * HW + trow0 + lrow) * EDIM;
            float s1 = 0.f, s2 = 0.f;
#pragma unroll
            for (int c = 0; c < 4; ++c) {
                const int off = (c * 16 + j) * 4;
                const float4 x = *reinterpret_cast<const float4*>(xa + off);
                *reinterpret_cast<float4*>(&stage[lrow][off]) = x;
                s1 += x.x + x.y + x.z + x.w;
                s2 += x.x * x.x + x.y * x.y + x.z * x.z + x.w * x.w;
            }
            s1 = rsum16(s1);
            s2 = rsum16(s2);
            mean_r[rr] = s1 * (1.0f / EDIM);
            rstd_r[rr] = rsqrtf(s2 * (1.0f / EDIM) - mean_r[rr] * mean_r[rr] + EPS_LN);
        }
        __syncthreads();

        // ---- dot: wave w computes full dots for slots 4w..4w+3, rows 0..31 ----
#pragma unroll
        for (int rb = 0; rb < 8; ++rb) {
            const int row = rb * 4 + gp;
            float d0 = 0.f, d1 = 0.f, d2 = 0.f, d3 = 0.f;
#pragma unroll
            for (int c = 0; c < 4; ++c) {
                const int off = (c * 16 + j) * 4;
                const float4 x = *reinterpret_cast<const float4*>(&stage[row][off]);
                d0 += x.x * Greg[0][c].x + x.y * Greg[0][c].y + x.z * Greg[0][c].z + x.w * Greg[0][c].w;
                d1 += x.x * Greg[1][c].x + x.y * Greg[1][c].y + x.z * Greg[1][c].z + x.w * Greg[1][c].w;
                d2 += x.x * Greg[2][c].x + x.y * Greg[2][c].y + x.z * Greg[2][c].z + x.w * Greg[2][c].w;
                d3 += x.x * Greg[3][c].x + x.y * Greg[3][c].y + x.z * Greg[3][c].z + x.w * Greg[3][c].w;
            }
            d0 = rsum16(d0); d1 = rsum16(d1); d2 = rsum16(d2); d3 = rsum16(d3);
            if (j == 0)
                *reinterpret_cast<float4*>(&logit_lds[row][w * 4]) =
                    make_float4(d0, d1, d2, d3);
        }
        __syncthreads();

        // ---- softmax: thread (g,j) handles rows g and g+16, slot j ----
#pragma unroll
        for (int rr = 0; rr < 2; ++rr) {
            const int lrow = g + rr * 16;
            float L = logit_lds[lrow][j];
            L = rstd_r[rr] * (L - mean_r[rr] * gqj) + bqj;
            const float mx = rmax16(L);
            const float p = __expf(L - mx);
            const float tot = rsum16(p);
            const float at = p / tot;
            wrec[lrow][j] = at;
            if (j == 0) {
                wrec[lrow][16] = rstd_r[rr];
                wrec[lrow][17] = rstd_r[rr] * mean_r[rr];
            }
            if (LAST)
                attn_out[((size_t)(b * NS + j)) * HW + trow0 + lrow] = at;
        }
        __syncthreads();

        // ---- phase B: wave w accumulates slots 4w..4w+3 from staged x ----
        {
            const int ch = lane * 4;
            const int sbase = w * 4;
#pragma unroll
            for (int r = 0; r < TROWS; ++r) {
                const float4 xv = *reinterpret_cast<const float4*>(&stage[r][ch]);
                const float4 at = *reinterpret_cast<const float4*>(&wrec[r][sbase]);
                const float rr = wrec[r][16];
                const float rm = wrec[r][17];
                float wg;
                wg = at.x * rr;
                acc[0][0] += wg * xv.x; acc[0][1] += wg * xv.y;
                acc[0][2] += wg * xv.z; acc[0][3] += wg * xv.w;
                S[0] += at.x; A[0] += at.x * rm;
                wg = at.y * rr;
                acc[1][0] += wg * xv.x; acc[1][1] += wg * xv.y;
                acc[1][2] += wg * xv.z; acc[1][3] += wg * xv.w;
                S[1] += at.y; A[1] += at.y * rm;
                wg = at.z * rr;
                acc[2][0] += wg * xv.x; acc[2][1] += wg * xv.y;
                acc[2][2] += wg * xv.z; acc[2][3] += wg * xv.w;
                S[2] += at.z; A[2] += at.z * rm;
                wg = at.w * rr;
                acc[3][0] += wg * xv.x; acc[3][1] += wg * xv.y;
                acc[3][2] += wg * xv.z; acc[3][3] += wg * xv.w;
                S[3] += at.w; A[3] += at.w * rm;
            }
        }
        __syncthreads();
    }

    // epilogue: each wave writes its own 4 slots
#pragma unroll
    for (int si = 0; si < 4; ++si) {
        *reinterpret_cast<float4*>(
            pacc + ((size_t)blockIdx.x * NS + w * 4 + si) * EDIM + lane * 4) =
            make_float4(acc[si][0], acc[si][1], acc[si][2], acc[si][3]);
    }
    if (lane == 0) {
#pragma unroll
        for (int si = 0; si < 4; ++si) {
            psum[blockIdx.x * 32 + w * 4 + si] = S[si];
            psum[blockIdx.x * 32 + 16 + w * 4 + si] = A[si];
        }
    }
}

// G1: partial reduce + ub + updates = ub @ w_v.T.  grid 256: (rt 0..127) x (ct 0..1)
__global__ __launch_bounds__(256) void k_upd(
    const float* __restrict__ pacc, const float* __restrict__ psum,
    const float* __restrict__ g_kv, const float* __restrict__ b_kv,
    const float* __restrict__ w_vT, float* __restrict__ updates) {
    const int rt = blockIdx.x >> 1;
    const int ct = blockIdx.x & 1;
    const int row0 = rt * 4;
    const int b = row0 >> 4;
    const int s0 = row0 & 15;
    const int t = threadIdx.x;
    __shared__ __align__(16) float ub[4][EDIM];
    __shared__ float sSA[4][2];

    if (t < 8) {
        const int r = t & 3;
        const int isA = t >> 2;
        float v = 0.f;
        for (int p = 0; p < BPB; ++p)
            v += psum[(b * BPB + p) * 32 + isA * 16 + s0 + r];
        sSA[r][isA] = v;
    }
    __syncthreads();
#pragma unroll
    for (int r = 0; r < 4; ++r) {
        float V = 0.f;
        for (int p = 0; p < BPB; ++p)
            V += pacc[((size_t)(b * BPB + p) * NS + s0 + r) * EDIM + t];
        const float Sv = sSA[r][0], Av = sSA[r][1];
        ub[r][t] = (g_kv[t] * (V - Av) + b_kv[t] * Sv) / (Sv + EPS_ATTN);
    }
    __syncthreads();

    const int c = ct * 128 + (t & 127);
    const int half = t >> 7;       // 2 rows per thread
    const float* u0 = ub[2 * half];
    const float* u1 = ub[2 * half + 1];
    float a0 = 0.f, a1 = 0.f;
#pragma unroll 4
    for (int j = 0; j < EDIM; j += 4) {
        const float4 x0 = *reinterpret_cast<const float4*>(u0 + j);
        const float4 x1 = *reinterpret_cast<const float4*>(u1 + j);
        const float w0 = w_vT[(size_t)j * EDIM + c];
        const float w1 = w_vT[(size_t)(j + 1) * EDIM + c];
        const float w2 = w_vT[(size_t)(j + 2) * EDIM + c];
        const float w3 = w_vT[(size_t)(j + 3) * EDIM + c];
        a0 += x0.x * w0 + x0.y * w1 + x0.z * w2 + x0.w * w3;
        a1 += x1.x * w0 + x1.y * w1 + x1.z * w2 + x1.w * w3;
    }
    updates[(size_t)(row0 + 2 * half) * EDIM + c] = a0;
    updates[(size_t)(row0 + 2 * half + 1) * EDIM + c] = a1;
}

// G2a: gi = upd @ w_ih.T + b_ih (ct 0..2), gh = qprev @ w_hh.T + b_hh (ct 3..5).
// grid 768: rt = bid/6 (4 rows), ct = bid%6 (256 cols).
__global__ __launch_bounds__(256) void k_gates(
    const float* __restrict__ updates, const float* __restrict__ qprev,
    const float* __restrict__ w_ihT, const float* __restrict__ w_hhT,
    const float* __restrict__ b_ih, const float* __restrict__ b_hh,
    float* __restrict__ gig) {
    const int rt = blockIdx.x / 6;
    const int ct = blockIdx.x % 6;
    const int row0 = rt * 4;
    const int t = threadIdx.x;
    const bool ih = ct < 3;
    const int lc = (ih ? ct : ct - 3) * 256 + t;   // 0..767
    const float* __restrict__ src = ih ? updates : qprev;
    const float* __restrict__ wT = ih ? w_ihT : w_hhT;

    __shared__ __align__(16) float in4[4][EDIM];
#pragma unroll
    for (int r = 0; r < 4; ++r)
        in4[r][t] = src[(size_t)(row0 + r) * EDIM + t];
    __syncthreads();

    float a0 = 0.f, a1 = 0.f, a2 = 0.f, a3 = 0.f;
#pragma unroll 4
    for (int j = 0; j < EDIM; j += 4) {
        const float4 x0 = *reinterpret_cast<const float4*>(&in4[0][j]);
        const float4 x1 = *reinterpret_cast<const float4*>(&in4[1][j]);
        const float4 x2 = *reinterpret_cast<const float4*>(&in4[2][j]);
        const float4 x3 = *reinterpret_cast<const float4*>(&in4[3][j]);
        const float w0 = wT[(size_t)j * 768 + lc];
        const float w1 = wT[(size_t)(j + 1) * 768 + lc];
        const float w2 = wT[(size_t)(j + 2) * 768 + lc];
        const float w3 = wT[(size_t)(j + 3) * 768 + lc];
        a0 += x0.x * w0 + x0.y * w1 + x0.z * w2 + x0.w * w3;
        a1 += x1.x * w0 + x1.y * w1 + x1.z * w2 + x1.w * w3;
        a2 += x2.x * w0 + x2.y * w1 + x2.z * w2 + x2.w * w3;
        a3 += x3.x * w0 + x3.y * w1 + x3.z * w2 + x3.w * w3;
    }
    const float bias = ih ? b_ih[lc] : b_hh[lc];
    const int gcol = ih ? lc : 768 + lc;
    gig[(size_t)(row0 + 0) * 1536 + gcol] = a0 + bias;
    gig[(size_t)(row0 + 1) * 1536 + gcol] = a1 + bias;
    gig[(size_t)(row0 + 2) * 1536 + gcol] = a2 + bias;
    gig[(size_t)(row0 + 3) * 1536 + gcol] = a3 + bias;
}

// G2b+G3 fused: recompute GRU pointwise + LN for this block's 4 rows, then
// h1 slice = gelu(ln2 @ w_f1T[:, ct*256..+255] + b_f1).
// grid 512: rt = bid>>2 (4 rows), ct = bid&3 (256 cols).
__global__ __launch_bounds__(256) void k_gruffn1(
    const float* __restrict__ gig, const float* __restrict__ qprev,
    const float* __restrict__ g_2, const float* __restrict__ b_2,
    const float* __restrict__ w_f1T, const float* __restrict__ b_f1,
    float* __restrict__ slots, float* __restrict__ h1) {
    const int rt = blockIdx.x >> 2;
    const int ct = blockIdx.x & 3;
    const int row0 = rt * 4;
    const int t = threadIdx.x;
    const int wave = t >> 6, lane = t & 63;
    __shared__ __align__(16) float ln2[4][EDIM];
    __shared__ float red[4][8];

    float sl[4];
#pragma unroll
    for (int r = 0; r < 4; ++r) {
        const size_t base = (size_t)(row0 + r) * 1536;
        const float ir = gig[base + t];
        const float iz = gig[base + 256 + t];
        const float inn = gig[base + 512 + t];
        const float hr = gig[base + 768 + t];
        const float hz = gig[base + 1024 + t];
        const float hn = gig[base + 1280 + t];
        const float h = qprev[(size_t)(row0 + r) * EDIM + t];
        const float rg = sigmoidf_(ir + hr);
        const float z = sigmoidf_(iz + hz);
        const float n = tanhf(inn + rg * hn);
        sl[r] = (1.0f - z) * n + z * h;
    }
    if (ct == 0) {
#pragma unroll
        for (int r = 0; r < 4; ++r)
            slots[(size_t)(row0 + r) * EDIM + t] = sl[r];
    }
    {
        float a[4], qq[4];
#pragma unroll
        for (int r = 0; r < 4; ++r) { a[r] = sl[r]; qq[r] = sl[r] * sl[r]; }
#pragma unroll
        for (int m = 1; m < 64; m <<= 1) {
#pragma unroll
            for (int r = 0; r < 4; ++r) {
                a[r] += __shfl_xor(a[r], m);
                qq[r] += __shfl_xor(qq[r], m);
            }
        }
        if (lane == 0) {
#pragma unroll
            for (int r = 0; r < 4; ++r) { red[wave][r] = a[r]; red[wave][4 + r] = qq[r]; }
        }
    }
    __syncthreads();
    {
        const float g = g_2[t], bb = b_2[t];
#pragma unroll
        for (int r = 0; r < 4; ++r) {
            const float Sv = red[0][r] + red[1][r] + red[2][r] + red[3][r];
            const float Qv = red[0][4 + r] + red[1][4 + r] + red[2][4 + r] + red[3][4 + r];
            const float mn = Sv * (1.0f / EDIM);
            const float rs = rsqrtf(Qv * (1.0f / EDIM) - mn * mn + EPS_LN);
            ln2[r][t] = (sl[r] - mn) * rs * g + bb;
        }
    }
    __syncthreads();

    const int c = ct * 256 + t;
    float a0 = 0.f, a1 = 0.f, a2 = 0.f, a3 = 0.f;
#pragma unroll 4
    for (int j = 0; j < EDIM; j += 4) {
        const float4 x0 = *reinterpret_cast<const float4*>(&ln2[0][j]);
        const float4 x1 = *reinterpret_cast<const float4*>(&ln2[1][j]);
        const float4 x2 = *reinterpret_cast<const float4*>(&ln2[2][j]);
        const float4 x3 = *reinterpret_cast<const float4*>(&ln2[3][j]);
        const float w0 = w_f1T[(size_t)j * FFND + c];
        const float w1 = w_f1T[(size_t)(j + 1) * FFND + c];
        const float w2 = w_f1T[(size_t)(j + 2) * FFND + c];
        const float w3 = w_f1T[(size_t)(j + 3) * FFND + c];
        a0 += x0.x * w0 + x0.y * w1 + x0.z * w2 + x0.w * w3;
        a1 += x1.x * w0 + x1.y * w1 + x1.z * w2 + x1.w * w3;
        a2 += x2.x * w0 + x2.y * w1 + x2.z * w2 + x2.w * w3;
        a3 += x3.x * w0 + x3.y * w1 + x3.z * w2 + x3.w * w3;
    }
    const float bf = b_f1[c];
    h1[(size_t)(row0 + 0) * FFND + c] = gelu_(a0 + bf);
    h1[(size_t)(row0 + 1) * FFND + c] = gelu_(a1 + bf);
    h1[(size_t)(row0 + 2) * FFND + c] = gelu_(a2 + bf);
    h1[(size_t)(row0 + 3) * FFND + c] = gelu_(a3 + bf);
}

// G4+G5 fused: q = slots + h1 @ w_f2.T + b_f2 (+adjust), then (if do_qpk)
// LN(q) @ W and gq/bq scalars.  grid 256 blocks x 2 rows.
__global__ __launch_bounds__(256) void k_ffn2qpk(
    const float* __restrict__ h1, const float* __restrict__ slots,
    const float* __restrict__ w_f2T, const float* __restrict__ b_f2,
    const float* __restrict__ query,
    const float* __restrict__ g_q, const float* __restrict__ b_q,
    const float* __restrict__ W,
    const float* __restrict__ g_kv, const float* __restrict__ b_kv,
    float* __restrict__ q_out, float* __restrict__ qpk, float* __restrict__ gqbq,
    int adjust, int do_qpk) {
    const int row0 = blockIdx.x * 2;
    const int t = threadIdx.x;
    const int wave = t >> 6, lane = t & 63;
    __shared__ __align__(16) float in2[2][FFND];
    __shared__ float red[4][4];
    __shared__ __align__(16) float qn[2][EDIM];

#pragma unroll
    for (int r = 0; r < 2; ++r)
        *reinterpret_cast<float4*>(&in2[r][t * 4]) =
            *reinterpret_cast<const float4*>(h1 + (size_t)(row0 + r) * FFND + t * 4);
    __syncthreads();
    float a0 = 0.f, a1 = 0.f;
#pragma unroll 4
    for (int j = 0; j < FFND; j += 4) {
        const float4 x0 = *reinterpret_cast<const float4*>(&in2[0][j]);
        const float4 x1 = *reinterpret_cast<const float4*>(&in2[1][j]);
        const float w0 = w_f2T[(size_t)j * EDIM + t];
        const float w1 = w_f2T[(size_t)(j + 1) * EDIM + t];
        const float w2 = w_f2T[(size_t)(j + 2) * EDIM + t];
        const float w3 = w_f2T[(size_t)(j + 3) * EDIM + t];
        a0 += x0.x * w0 + x0.y * w1 + x0.z * w2 + x0.w * w3;
        a1 += x1.x * w0 + x1.y * w1 + x1.z * w2 + x1.w * w3;
    }
    const float bf = b_f2[t];
    float v0 = slots[(size_t)row0 * EDIM + t] + a0 + bf;
    float v1 = slots[(size_t)(row0 + 1) * EDIM + t] + a1 + bf;
    if (adjust) {
        const float qq0 = query[(size_t)row0 * EDIM + t];
        const float qq1 = query[(size_t)(row0 + 1) * EDIM + t];
        v0 = (v0 + qq0) - qq0;
        v1 = (v1 + qq1) - qq1;
    }
    q_out[(size_t)row0 * EDIM + t] = v0;
    q_out[(size_t)(row0 + 1) * EDIM + t] = v1;

    if (!do_qpk) return;

    {
        float a0r = v0, q0 = v0 * v0, a1r = v1, q1 = v1 * v1;
#pragma unroll
        for (int m = 1; m < 64; m <<= 1) {
            a0r += __shfl_xor(a0r, m); q0 += __shfl_xor(q0, m);
            a1r += __shfl_xor(a1r, m); q1 += __shfl_xor(q1, m);
        }
        if (lane == 0) { red[wave][0] = a0r; red[wave][1] = q0; red[wave][2] = a1r; red[wave][3] = q1; }
    }
    __syncthreads();
    {
        const float S0 = red[0][0] + red[1][0] + red[2][0] + red[3][0];
        const float Q0 = red[0][1] + red[1][1] + red[2][1] + red[3][1];
        const float S1 = red[0][2] + red[1][2] + red[2][2] + red[3][2];
        const float Q1 = red[0][3] + red[1][3] + red[2][3] + red[3][3];
        const float m0 = S0 * (1.0f / EDIM);
        const float r0 = rsqrtf(Q0 * (1.0f / EDIM) - m0 * m0 + EPS_LN);
        const float m1 = S1 * (1.0f / EDIM);
        const float r1 = rsqrtf(Q1 * (1.0f / EDIM) - m1 * m1 + EPS_LN);
        const float g = g_q[t], bb = b_q[t];
        qn[0][t] = (v0 - m0) * r0 * g + bb;
        qn[1][t] = (v1 - m1) * r1 * g + bb;
    }
    __syncthreads();
    float p0 = 0.f, p1 = 0.f;
#pragma unroll 4
    for (int j = 0; j < EDIM; j += 4) {
        const float4 x0 = *reinterpret_cast<const float4*>(&qn[0][j]);
        const float4 x1 = *reinterpret_cast<const float4*>(&qn[1][j]);
        const float w0 = W[(size_t)j * EDIM + t];
        const float w1 = W[(size_t)(j + 1) * EDIM + t];
        const float w2 = W[(size_t)(j + 2) * EDIM + t];
        const float w3 = W[(size_t)(j + 3) * EDIM + t];
        p0 += x0.x * w0 + x0.y * w1 + x0.z * w2 + x0.w * w3;
        p1 += x1.x * w0 + x1.y * w1 + x1.z * w2 + x1.w * w3;
    }
    qpk[(size_t)row0 * EDIM + t] = p0;
    qpk[(size_t)(row0 + 1) * EDIM + t] = p1;
    {
        const float gk = g_kv[t], bk = b_kv[t];
        float u0 = p0 * gk, w0 = p0 * bk, u1 = p1 * gk, w1 = p1 * bk;
#pragma unroll
        for (int m = 1; m < 64; m <<= 1) {
            u0 += __shfl_xor(u0, m); w0 += __shfl_xor(w0, m);
            u1 += __shfl_xor(u1, m); w1 += __shfl_xor(w1, m);
        }
        __syncthreads();
        if (lane == 0) { red[wave][0] = u0; red[wave][1] = w0; red[wave][2] = u1; red[wave][3] = w1; }
        __syncthreads();
        if (t == 0) {
            const int b = row0 >> 4;
            const int sl = row0 & 15;
            gqbq[b * 32 + sl] = red[0][0] + red[1][0] + red[2][0] + red[3][0];
            gqbq[b * 32 + 16 + sl] = red[0][1] + red[1][1] + red[2][1] + red[3][1];
            gqbq[b * 32 + sl + 1] = red[0][2] + red[1][2] + red[2][2] + red[3][2];
            gqbq[b * 32 + 16 + sl + 1] = red[0][3] + red[1][3] + red[2][3] + red[3][3];
        }
    }
}

extern "C" void kernel_launch(void* const* d_in, const int* in_sizes, int n_in,
                              void* d_out, int out_size, void* d_ws, size_t ws_size,
                              hipStream_t stream) {
    const float* input = (const float*)d_in[0];
    const float* query = (const float*)d_in[1];
    const float* g_kv = (const float*)d_in[2];
    const float* b_kv = (const float*)d_in[3];
    const float* w_k = (const float*)d_in[4];
    const float* w_v = (const float*)d_in[5];
    const float* g_q = (const float*)d_in[6];
    const float* b_q = (const float*)d_in[7];
    const float* w_q = (const float*)d_in[8];
    const float* w_ih = (const float*)d_in[9];
    const float* w_hh = (const float*)d_in[10];
    const float* b_ih = (const float*)d_in[11];
    const float* b_hh = (const float*)d_in[12];
    const float* g_2 = (const float*)d_in[13];
    const float* b_2 = (const float*)d_in[14];
    const float* w_f1 = (const float*)d_in[15];
    const float* b_f1 = (const float*)d_in[16];
    const float* w_f2 = (const float*)d_in[17];
    const float* b_f2 = (const float*)d_in[18];

    float* ws = (float*)d_ws;
    float* W = ws;        ws += 65536;
    float* qpk = ws;      ws += 131072;
    float* gqbq = ws;     ws += 1024;
    float* psum = ws;     ws += 32768;
    float* q_ws = ws;     ws += 131072;
    float* updates = ws;  ws += 131072;
    float* slots = ws;    ws += 131072;
    float* w_vT = ws;     ws += 65536;
    float* w_ihT = ws;    ws += 196608;
    float* w_hhT = ws;    ws += 196608;
    float* w_f1T = ws;    ws += 262144;
    float* w_f2T = ws;    ws += 262144;
    float* pacc = ws;     ws += (size_t)NB * BPB * NS * EDIM;   // 16 MB
    float* gig = pacc;                        // 512*1536 overlay (after k_upd)
    float* h1 = pacc + 786432;                // 512*1024 overlay

    float* out_q = (float*)d_out;
    float* out_attn = out_q + (size_t)NB * NS * EDIM;

    k_prep<<<256, 256, 0, stream>>>(w_q, w_k, W);
    k_tr<<<16, 256, 0, stream>>>(w_v, w_vT, 256, 256);
    k_tr<<<48, 256, 0, stream>>>(w_ih, w_ihT, 768, 256);
    k_tr<<<48, 256, 0, stream>>>(w_hh, w_hhT, 768, 256);
    k_tr<<<64, 256, 0, stream>>>(w_f1, w_f1T, 1024, 256);
    k_tr<<<64, 256, 0, stream>>>(w_f2, w_f2T, 256, 1024);
    k_qproj<<<512, 256, 0, stream>>>(query, g_q, b_q, W, g_kv, b_kv, qpk, gqbq);

    const float* qprev[3] = {query, q_ws, q_ws};
    float* qdst[3] = {q_ws, q_ws, out_q};
    const int adj[3] = {0, 1, 0};

    for (int it = 0; it < 3; ++it) {
        const bool last = (it == 2);
        if (last)
            k_bigpass<true><<<NB * BPB, 256, 0, stream>>>(input, qpk, gqbq, g_kv, pacc, psum, out_attn);
        else
            k_bigpass<false><<<NB * BPB, 256, 0, stream>>>(input, qpk, gqbq, g_kv, pacc, psum, nullptr);
        k_upd<<<256, 256, 0, stream>>>(pacc, psum, g_kv, b_kv, w_vT, updates);
        k_gates<<<768, 256, 0, stream>>>(updates, qprev[it], w_ihT, w_hhT, b_ih, b_hh, gig);
        k_gruffn1<<<512, 256, 0, stream>>>(gig, qprev[it], g_2, b_2, w_f1T, b_f1, slots, h1);
        k_ffn2qpk<<<256, 256, 0, stream>>>(h1, slots, w_f2T, b_f2, query, g_q, b_q, W,
                                           g_kv, b_kv, qdst[it], qpk, gqbq,
                                           adj[it], last ? 0 : 1);
    }
}

// Round 18
// 462.536 us; speedup vs baseline: 2.8476x; 1.0188x over previous
//
#include <hip/hip_runtime.h>
#include <math.h>

#define NB 32
#define HW 4096
#define NS 16
#define EDIM 256
#define FFND 1024
#define EPS_LN 1e-5f
#define EPS_ATTN 1e-5f
#define BPB 32            // sub-blocks per batch in bigpass
#define RPB 128           // rows per bigpass block (HW/BPB)
#define TROWS 16          // rows per barrier-tile (v10: back to 16; v9's 32 regressed)

__device__ __forceinline__ float sigmoidf_(float x) { return 1.0f / (1.0f + __expf(-x)); }
__device__ __forceinline__ float gelu_(float x) {
    float x3 = x * x * x;
    return 0.5f * x * (1.0f + tanhf(0.7978845608028654f * (x + 0.044715f * x3)));
}

// Sum across the 16-lane DPP row via row_ror rotations — pure VALU pipe.
__device__ __forceinline__ float rsum16(float v) {
    int x;
    x = __builtin_amdgcn_update_dpp(0, __float_as_int(v), 0x128, 0xF, 0xF, true); // ror:8
    v += __int_as_float(x);
    x = __builtin_amdgcn_update_dpp(0, __float_as_int(v), 0x124, 0xF, 0xF, true); // ror:4
    v += __int_as_float(x);
    x = __builtin_amdgcn_update_dpp(0, __float_as_int(v), 0x122, 0xF, 0xF, true); // ror:2
    v += __int_as_float(x);
    x = __builtin_amdgcn_update_dpp(0, __float_as_int(v), 0x121, 0xF, 0xF, true); // ror:1
    v += __int_as_float(x);
    return v;
}
// Max across the 16-lane DPP row.
__device__ __forceinline__ float rmax16(float v) {
    int x;
    x = __builtin_amdgcn_update_dpp(0, __float_as_int(v), 0x128, 0xF, 0xF, true);
    v = fmaxf(v, __int_as_float(x));
    x = __builtin_amdgcn_update_dpp(0, __float_as_int(v), 0x124, 0xF, 0xF, true);
    v = fmaxf(v, __int_as_float(x));
    x = __builtin_amdgcn_update_dpp(0, __float_as_int(v), 0x122, 0xF, 0xF, true);
    v = fmaxf(v, __int_as_float(x));
    x = __builtin_amdgcn_update_dpp(0, __float_as_int(v), 0x121, 0xF, 0xF, true);
    v = fmaxf(v, __int_as_float(x));
    return v;
}

// W[j][c] = scale * sum_e w_q[e][j] * w_k[e][c]   (scale = 256^-0.5 = 1/16)
__global__ void k_prep(const float* __restrict__ w_q, const float* __restrict__ w_k,
                       float* __restrict__ W) {
    const int j = blockIdx.x;
    const int c = threadIdx.x;
    float acc = 0.f;
    for (int e = 0; e < EDIM; ++e)
        acc += w_q[e * EDIM + j] * w_k[e * EDIM + c];
    W[j * EDIM + c] = acc * 0.0625f;
}

// Tiled transpose: src[R][C] -> dst[C][R].  R,C multiples of 64. 64x64 tiles.
__global__ __launch_bounds__(256) void k_tr(const float* __restrict__ src,
                                            float* __restrict__ dst, int R, int C) {
    __shared__ float tile[64][65];
    const int tilesC = C >> 6;
    const int tR = (blockIdx.x / tilesC) << 6;
    const int tC = (blockIdx.x % tilesC) << 6;
    const int t = threadIdx.x;
    {
        const int r = t >> 2;
        const int c0 = (t & 3) << 4;
#pragma unroll
        for (int i = 0; i < 16; i += 4) {
            const float4 v = *reinterpret_cast<const float4*>(src + (size_t)(tR + r) * C + tC + c0 + i);
            tile[r][c0 + i] = v.x; tile[r][c0 + i + 1] = v.y;
            tile[r][c0 + i + 2] = v.z; tile[r][c0 + i + 3] = v.w;
        }
    }
    __syncthreads();
    {
        const int c = t >> 2;
        const int r0 = (t & 3) << 4;
#pragma unroll
        for (int i = 0; i < 16; ++i)
            dst[(size_t)(tC + c) * R + tR + r0 + i] = tile[r0 + i][c];
    }
}

// Iteration-0 only: qn = LN(query_row); qpk = qn @ W; gq/bq scalars.
__global__ void k_qproj(const float* __restrict__ qsrc, const float* __restrict__ g_q,
                        const float* __restrict__ b_q, const float* __restrict__ W,
                        const float* __restrict__ g_kv, const float* __restrict__ b_kv,
                        float* __restrict__ qpk, float* __restrict__ gqbq) {
    const int row = blockIdx.x;   // 0..511  (= b*16 + s)
    const int t = threadIdx.x;
    __shared__ float qn[EDIM];
    __shared__ float red[16];
    const float v = qsrc[(size_t)row * EDIM + t];
    float s = v, ss = v * v;
#pragma unroll
    for (int m = 1; m < 64; m <<= 1) { s += __shfl_xor(s, m); ss += __shfl_xor(ss, m); }
    const int wave = t >> 6, lane = t & 63;
    if (lane == 0) { red[wave] = s; red[8 + wave] = ss; }
    __syncthreads();
    const float st = red[0] + red[1] + red[2] + red[3];
    const float sst = red[8] + red[9] + red[10] + red[11];
    const float mean = st * (1.0f / EDIM);
    const float rstd = rsqrtf(sst * (1.0f / EDIM) - mean * mean + EPS_LN);
    qn[t] = (v - mean) * rstd * g_q[t] + b_q[t];
    __syncthreads();
    float acc = 0.f;
    for (int j = 0; j < EDIM; ++j)
        acc += qn[j] * W[j * EDIM + t];
    qpk[(size_t)row * EDIM + t] = acc;
    float u = acc * g_kv[t];
    float w2 = acc * b_kv[t];
#pragma unroll
    for (int m = 1; m < 64; m <<= 1) { u += __shfl_xor(u, m); w2 += __shfl_xor(w2, m); }
    __syncthreads();
    if (lane == 0) { red[wave] = u; red[8 + wave] = w2; }
    __syncthreads();
    if (t == 0) {
        const int b = row >> 4, sl = row & 15;
        gqbq[b * 32 + sl] = red[0] + red[1] + red[2] + red[3];
        gqbq[b * 32 + 16 + sl] = red[8] + red[9] + red[10] + red[11];
    }
}

// Streaming pass v10: v8 (G in regs, slot-split dot, DPP reductions, TROWS=16)
// + T14-style register prefetch: tile t+1's global loads are issued right after
// the stage barrier, held in 4 float4 regs, written to LDS at the next tile top.
// Removes the ~500-900cyc load latency from the per-tile critical path (r17
// showed barriers are NOT the residual; load latency is the remaining serial).
template <bool LAST>
__global__ __launch_bounds__(256, 2) void k_bigpass(
    const float* __restrict__ input, const float* __restrict__ qpk,
    const float* __restrict__ gqbq, const float* __restrict__ g_kv,
    float* __restrict__ pacc, float* __restrict__ psum, float* __restrict__ attn_out) {
    const int b = blockIdx.x >> 5;        // /BPB
    const int sub = blockIdx.x & 31;      // %BPB
    const int t = threadIdx.x;
    const int w = t >> 6;        // wave id -> slots 4w..4w+3
    const int lane = t & 63;
    const int gp = (t >> 4) & 3; // row-subgroup within wave (dot phase)
    const int g = t >> 4;        // row 0..15 (staging/softmax)
    const int j = t & 15;        // channel-16th (staging/dot) == slot idx (softmax)

    __shared__ __align__(16) float stage[TROWS][264];   // 16.9 KB padded
    __shared__ __align__(16) float wrec[TROWS][20];     // attn[16], rstd, rstd*mean
    __shared__ __align__(16) float logit_lds[TROWS][NS];

    // per-slot scalars (j = slot index in softmax phase)
    const float gqj = gqbq[b * 32 + j];
    const float bqj = gqbq[b * 32 + 16 + j];

    // G registers: slots 4w..4w+3, this lane's channels j*4+64c (c=0..3)
    float4 Greg[4][4];
#pragma unroll
    for (int sp = 0; sp < 4; ++sp) {
#pragma unroll
        for (int c = 0; c < 4; ++c) {
            const int off = (c * 16 + j) * 4;
            const float4 qv = *reinterpret_cast<const float4*>(
                qpk + (size_t)b * 4096 + (w * 4 + sp) * 256 + off);
            const float4 gv = *reinterpret_cast<const float4*>(g_kv + off);
            Greg[sp][c] = make_float4(qv.x * gv.x, qv.y * gv.y, qv.z * gv.z, qv.w * gv.w);
        }
    }

    float acc[4][4];
    float S[4], A[4];
#pragma unroll
    for (int si = 0; si < 4; ++si) {
        acc[si][0] = acc[si][1] = acc[si][2] = acc[si][3] = 0.f;
        S[si] = 0.f; A[si] = 0.f;
    }

    const int rowbase = sub * RPB;

    // prologue: prefetch tile 0 into registers
    float4 xh[4];
    {
        const float* xa = input + ((size_t)b * HW + rowbase + g) * EDIM;
#pragma unroll
        for (int c = 0; c < 4; ++c)
            xh[c] = *reinterpret_cast<const float4*>(xa + (c * 16 + j) * 4);
    }

#pragma unroll 1
    for (int tt = 0; tt < RPB / TROWS; ++tt) {
        const int grow = rowbase + tt * TROWS + g;

        // ---- stage held regs + LN stats (no global-load on critical path) ----
        float s1 = 0.f, s2 = 0.f;
#pragma unroll
        for (int c = 0; c < 4; ++c) {
            const int off = (c * 16 + j) * 4;
            *reinterpret_cast<float4*>(&stage[g][off]) = xh[c];
            s1 += xh[c].x + xh[c].y + xh[c].z + xh[c].w;
            s2 += xh[c].x * xh[c].x + xh[c].y * xh[c].y + xh[c].z * xh[c].z + xh[c].w * xh[c].w;
        }
        s1 = rsum16(s1);
        s2 = rsum16(s2);
        const float mean = s1 * (1.0f / EDIM);
        const float rstd = rsqrtf(s2 * (1.0f / EDIM) - mean * mean + EPS_LN);
        __syncthreads();

        // ---- issue next tile's loads early (latency hides under dot/softmax/phaseB)
        if (tt + 1 < RPB / TROWS) {
            const float* xn = input + ((size_t)b * HW + rowbase + (tt + 1) * TROWS + g) * EDIM;
#pragma unroll
            for (int c = 0; c < 4; ++c)
                xh[c] = *reinterpret_cast<const float4*>(xn + (c * 16 + j) * 4);
        }

        // ---- dot: wave w computes full dots for slots 4w..4w+3 ----
#pragma unroll
        for (int rb = 0; rb < 4; ++rb) {
            const int row = rb * 4 + gp;
            float d0 = 0.f, d1 = 0.f, d2 = 0.f, d3 = 0.f;
#pragma unroll
            for (int c = 0; c < 4; ++c) {
                const int off = (c * 16 + j) * 4;
                const float4 x = *reinterpret_cast<const float4*>(&stage[row][off]);
                d0 += x.x * Greg[0][c].x + x.y * Greg[0][c].y + x.z * Greg[0][c].z + x.w * Greg[0][c].w;
                d1 += x.x * Greg[1][c].x + x.y * Greg[1][c].y + x.z * Greg[1][c].z + x.w * Greg[1][c].w;
                d2 += x.x * Greg[2][c].x + x.y * Greg[2][c].y + x.z * Greg[2][c].z + x.w * Greg[2][c].w;
                d3 += x.x * Greg[3][c].x + x.y * Greg[3][c].y + x.z * Greg[3][c].z + x.w * Greg[3][c].w;
            }
            d0 = rsum16(d0); d1 = rsum16(d1); d2 = rsum16(d2); d3 = rsum16(d3);
            if (j == 0)
                *reinterpret_cast<float4*>(&logit_lds[row][w * 4]) =
                    make_float4(d0, d1, d2, d3);
        }
        __syncthreads();

        // ---- softmax: thread (row g, slot j) ----
        {
            float L = logit_lds[g][j];
            L = rstd * (L - mean * gqj) + bqj;
            const float mx = rmax16(L);
            const float p = __expf(L - mx);
            const float tot = rsum16(p);
            const float at = p / tot;
            wrec[g][j] = at;
            if (j == 0) {
                wrec[g][16] = rstd;
                wrec[g][17] = rstd * mean;
            }
            if (LAST)
                attn_out[((size_t)(b * NS + j)) * HW + grow] = at;
        }
        __syncthreads();

        // ---- phase B: wave w accumulates slots 4w..4w+3 from staged x ----
        {
            const int ch = lane * 4;
            const int sbase = w * 4;
#pragma unroll
            for (int r = 0; r < TROWS; ++r) {
                const float4 xv = *reinterpret_cast<const float4*>(&stage[r][ch]);
                const float4 at = *reinterpret_cast<const float4*>(&wrec[r][sbase]);
                const float rr = wrec[r][16];
                const float rm = wrec[r][17];
                float wg;
                wg = at.x * rr;
                acc[0][0] += wg * xv.x; acc[0][1] += wg * xv.y;
                acc[0][2] += wg * xv.z; acc[0][3] += wg * xv.w;
                S[0] += at.x; A[0] += at.x * rm;
                wg = at.y * rr;
                acc[1][0] += wg * xv.x; acc[1][1] += wg * xv.y;
                acc[1][2] += wg * xv.z; acc[1][3] += wg * xv.w;
                S[1] += at.y; A[1] += at.y * rm;
                wg = at.z * rr;
                acc[2][0] += wg * xv.x; acc[2][1] += wg * xv.y;
                acc[2][2] += wg * xv.z; acc[2][3] += wg * xv.w;
                S[2] += at.z; A[2] += at.z * rm;
                wg = at.w * rr;
                acc[3][0] += wg * xv.x; acc[3][1] += wg * xv.y;
                acc[3][2] += wg * xv.z; acc[3][3] += wg * xv.w;
                S[3] += at.w; A[3] += at.w * rm;
            }
        }
        __syncthreads();
    }

    // epilogue: each wave writes its own 4 slots
#pragma unroll
    for (int si = 0; si < 4; ++si) {
        *reinterpret_cast<float4*>(
            pacc + ((size_t)blockIdx.x * NS + w * 4 + si) * EDIM + lane * 4) =
            make_float4(acc[si][0], acc[si][1], acc[si][2], acc[si][3]);
    }
    if (lane == 0) {
#pragma unroll
        for (int si = 0; si < 4; ++si) {
            psum[blockIdx.x * 32 + w * 4 + si] = S[si];
            psum[blockIdx.x * 32 + 16 + w * 4 + si] = A[si];
        }
    }
}

// G1: partial reduce + ub + updates = ub @ w_v.T.  grid 256: (rt 0..127) x (ct 0..1)
__global__ __launch_bounds__(256) void k_upd(
    const float* __restrict__ pacc, const float* __restrict__ psum,
    const float* __restrict__ g_kv, const float* __restrict__ b_kv,
    const float* __restrict__ w_vT, float* __restrict__ updates) {
    const int rt = blockIdx.x >> 1;
    const int ct = blockIdx.x & 1;
    const int row0 = rt * 4;
    const int b = row0 >> 4;
    const int s0 = row0 & 15;
    const int t = threadIdx.x;
    __shared__ __align__(16) float ub[4][EDIM];
    __shared__ float sSA[4][2];

    if (t < 8) {
        const int r = t & 3;
        const int isA = t >> 2;
        float v = 0.f;
        for (int p = 0; p < BPB; ++p)
            v += psum[(b * BPB + p) * 32 + isA * 16 + s0 + r];
        sSA[r][isA] = v;
    }
    __syncthreads();
#pragma unroll
    for (int r = 0; r < 4; ++r) {
        float V = 0.f;
        for (int p = 0; p < BPB; ++p)
            V += pacc[((size_t)(b * BPB + p) * NS + s0 + r) * EDIM + t];
        const float Sv = sSA[r][0], Av = sSA[r][1];
        ub[r][t] = (g_kv[t] * (V - Av) + b_kv[t] * Sv) / (Sv + EPS_ATTN);
    }
    __syncthreads();

    const int c = ct * 128 + (t & 127);
    const int half = t >> 7;       // 2 rows per thread
    const float* u0 = ub[2 * half];
    const float* u1 = ub[2 * half + 1];
    float a0 = 0.f, a1 = 0.f;
#pragma unroll 4
    for (int j = 0; j < EDIM; j += 4) {
        const float4 x0 = *reinterpret_cast<const float4*>(u0 + j);
        const float4 x1 = *reinterpret_cast<const float4*>(u1 + j);
        const float w0 = w_vT[(size_t)j * EDIM + c];
        const float w1 = w_vT[(size_t)(j + 1) * EDIM + c];
        const float w2 = w_vT[(size_t)(j + 2) * EDIM + c];
        const float w3 = w_vT[(size_t)(j + 3) * EDIM + c];
        a0 += x0.x * w0 + x0.y * w1 + x0.z * w2 + x0.w * w3;
        a1 += x1.x * w0 + x1.y * w1 + x1.z * w2 + x1.w * w3;
    }
    updates[(size_t)(row0 + 2 * half) * EDIM + c] = a0;
    updates[(size_t)(row0 + 2 * half + 1) * EDIM + c] = a1;
}

// G2a: gi = upd @ w_ih.T + b_ih (ct 0..2), gh = qprev @ w_hh.T + b_hh (ct 3..5).
// grid 768: rt = bid/6 (4 rows), ct = bid%6 (256 cols).
__global__ __launch_bounds__(256) void k_gates(
    const float* __restrict__ updates, const float* __restrict__ qprev,
    const float* __restrict__ w_ihT, const float* __restrict__ w_hhT,
    const float* __restrict__ b_ih, const float* __restrict__ b_hh,
    float* __restrict__ gig) {
    const int rt = blockIdx.x / 6;
    const int ct = blockIdx.x % 6;
    const int row0 = rt * 4;
    const int t = threadIdx.x;
    const bool ih = ct < 3;
    const int lc = (ih ? ct : ct - 3) * 256 + t;   // 0..767
    const float* __restrict__ src = ih ? updates : qprev;
    const float* __restrict__ wT = ih ? w_ihT : w_hhT;

    __shared__ __align__(16) float in4[4][EDIM];
#pragma unroll
    for (int r = 0; r < 4; ++r)
        in4[r][t] = src[(size_t)(row0 + r) * EDIM + t];
    __syncthreads();

    float a0 = 0.f, a1 = 0.f, a2 = 0.f, a3 = 0.f;
#pragma unroll 4
    for (int j = 0; j < EDIM; j += 4) {
        const float4 x0 = *reinterpret_cast<const float4*>(&in4[0][j]);
        const float4 x1 = *reinterpret_cast<const float4*>(&in4[1][j]);
        const float4 x2 = *reinterpret_cast<const float4*>(&in4[2][j]);
        const float4 x3 = *reinterpret_cast<const float4*>(&in4[3][j]);
        const float w0 = wT[(size_t)j * 768 + lc];
        const float w1 = wT[(size_t)(j + 1) * 768 + lc];
        const float w2 = wT[(size_t)(j + 2) * 768 + lc];
        const float w3 = wT[(size_t)(j + 3) * 768 + lc];
        a0 += x0.x * w0 + x0.y * w1 + x0.z * w2 + x0.w * w3;
        a1 += x1.x * w0 + x1.y * w1 + x1.z * w2 + x1.w * w3;
        a2 += x2.x * w0 + x2.y * w1 + x2.z * w2 + x2.w * w3;
        a3 += x3.x * w0 + x3.y * w1 + x3.z * w2 + x3.w * w3;
    }
    const float bias = ih ? b_ih[lc] : b_hh[lc];
    const int gcol = ih ? lc : 768 + lc;
    gig[(size_t)(row0 + 0) * 1536 + gcol] = a0 + bias;
    gig[(size_t)(row0 + 1) * 1536 + gcol] = a1 + bias;
    gig[(size_t)(row0 + 2) * 1536 + gcol] = a2 + bias;
    gig[(size_t)(row0 + 3) * 1536 + gcol] = a3 + bias;
}

// G2b+G3 fused: recompute GRU pointwise + LN for this block's 4 rows, then
// h1 slice = gelu(ln2 @ w_f1T[:, ct*256..+255] + b_f1).
// grid 512: rt = bid>>2 (4 rows), ct = bid&3 (256 cols).
__global__ __launch_bounds__(256) void k_gruffn1(
    const float* __restrict__ gig, const float* __restrict__ qprev,
    const float* __restrict__ g_2, const float* __restrict__ b_2,
    const float* __restrict__ w_f1T, const float* __restrict__ b_f1,
    float* __restrict__ slots, float* __restrict__ h1) {
    const int rt = blockIdx.x >> 2;
    const int ct = blockIdx.x & 3;
    const int row0 = rt * 4;
    const int t = threadIdx.x;
    const int wave = t >> 6, lane = t & 63;
    __shared__ __align__(16) float ln2[4][EDIM];
    __shared__ float red[4][8];

    float sl[4];
#pragma unroll
    for (int r = 0; r < 4; ++r) {
        const size_t base = (size_t)(row0 + r) * 1536;
        const float ir = gig[base + t];
        const float iz = gig[base + 256 + t];
        const float inn = gig[base + 512 + t];
        const float hr = gig[base + 768 + t];
        const float hz = gig[base + 1024 + t];
        const float hn = gig[base + 1280 + t];
        const float h = qprev[(size_t)(row0 + r) * EDIM + t];
        const float rg = sigmoidf_(ir + hr);
        const float z = sigmoidf_(iz + hz);
        const float n = tanhf(inn + rg * hn);
        sl[r] = (1.0f - z) * n + z * h;
    }
    if (ct == 0) {
#pragma unroll
        for (int r = 0; r < 4; ++r)
            slots[(size_t)(row0 + r) * EDIM + t] = sl[r];
    }
    {
        float a[4], qq[4];
#pragma unroll
        for (int r = 0; r < 4; ++r) { a[r] = sl[r]; qq[r] = sl[r] * sl[r]; }
#pragma unroll
        for (int m = 1; m < 64; m <<= 1) {
#pragma unroll
            for (int r = 0; r < 4; ++r) {
                a[r] += __shfl_xor(a[r], m);
                qq[r] += __shfl_xor(qq[r], m);
            }
        }
        if (lane == 0) {
#pragma unroll
            for (int r = 0; r < 4; ++r) { red[wave][r] = a[r]; red[wave][4 + r] = qq[r]; }
        }
    }
    __syncthreads();
    {
        const float g = g_2[t], bb = b_2[t];
#pragma unroll
        for (int r = 0; r < 4; ++r) {
            const float Sv = red[0][r] + red[1][r] + red[2][r] + red[3][r];
            const float Qv = red[0][4 + r] + red[1][4 + r] + red[2][4 + r] + red[3][4 + r];
            const float mn = Sv * (1.0f / EDIM);
            const float rs = rsqrtf(Qv * (1.0f / EDIM) - mn * mn + EPS_LN);
            ln2[r][t] = (sl[r] - mn) * rs * g + bb;
        }
    }
    __syncthreads();

    const int c = ct * 256 + t;
    float a0 = 0.f, a1 = 0.f, a2 = 0.f, a3 = 0.f;
#pragma unroll 4
    for (int j = 0; j < EDIM; j += 4) {
        const float4 x0 = *reinterpret_cast<const float4*>(&ln2[0][j]);
        const float4 x1 = *reinterpret_cast<const float4*>(&ln2[1][j]);
        const float4 x2 = *reinterpret_cast<const float4*>(&ln2[2][j]);
        const float4 x3 = *reinterpret_cast<const float4*>(&ln2[3][j]);
        const float w0 = w_f1T[(size_t)j * FFND + c];
        const float w1 = w_f1T[(size_t)(j + 1) * FFND + c];
        const float w2 = w_f1T[(size_t)(j + 2) * FFND + c];
        const float w3 = w_f1T[(size_t)(j + 3) * FFND + c];
        a0 += x0.x * w0 + x0.y * w1 + x0.z * w2 + x0.w * w3;
        a1 += x1.x * w0 + x1.y * w1 + x1.z * w2 + x1.w * w3;
        a2 += x2.x * w0 + x2.y * w1 + x2.z * w2 + x2.w * w3;
        a3 += x3.x * w0 + x3.y * w1 + x3.z * w2 + x3.w * w3;
    }
    const float bf = b_f1[c];
    h1[(size_t)(row0 + 0) * FFND + c] = gelu_(a0 + bf);
    h1[(size_t)(row0 + 1) * FFND + c] = gelu_(a1 + bf);
    h1[(size_t)(row0 + 2) * FFND + c] = gelu_(a2 + bf);
    h1[(size_t)(row0 + 3) * FFND + c] = gelu_(a3 + bf);
}

// G4+G5 fused: q = slots + h1 @ w_f2.T + b_f2 (+adjust), then (if do_qpk)
// LN(q) @ W and gq/bq scalars.  grid 256 blocks x 2 rows.
__global__ __launch_bounds__(256) void k_ffn2qpk(
    const float* __restrict__ h1, const float* __restrict__ slots,
    const float* __restrict__ w_f2T, const float* __restrict__ b_f2,
    const float* __restrict__ query,
    const float* __restrict__ g_q, const float* __restrict__ b_q,
    const float* __restrict__ W,
    const float* __restrict__ g_kv, const float* __restrict__ b_kv,
    float* __restrict__ q_out, float* __restrict__ qpk, float* __restrict__ gqbq,
    int adjust, int do_qpk) {
    const int row0 = blockIdx.x * 2;
    const int t = threadIdx.x;
    const int wave = t >> 6, lane = t & 63;
    __shared__ __align__(16) float in2[2][FFND];
    __shared__ float red[4][4];
    __shared__ __align__(16) float qn[2][EDIM];

#pragma unroll
    for (int r = 0; r < 2; ++r)
        *reinterpret_cast<float4*>(&in2[r][t * 4]) =
            *reinterpret_cast<const float4*>(h1 + (size_t)(row0 + r) * FFND + t * 4);
    __syncthreads();
    float a0 = 0.f, a1 = 0.f;
#pragma unroll 4
    for (int j = 0; j < FFND; j += 4) {
        const float4 x0 = *reinterpret_cast<const float4*>(&in2[0][j]);
        const float4 x1 = *reinterpret_cast<const float4*>(&in2[1][j]);
        const float w0 = w_f2T[(size_t)j * EDIM + t];
        const float w1 = w_f2T[(size_t)(j + 1) * EDIM + t];
        const float w2 = w_f2T[(size_t)(j + 2) * EDIM + t];
        const float w3 = w_f2T[(size_t)(j + 3) * EDIM + t];
        a0 += x0.x * w0 + x0.y * w1 + x0.z * w2 + x0.w * w3;
        a1 += x1.x * w0 + x1.y * w1 + x1.z * w2 + x1.w * w3;
    }
    const float bf = b_f2[t];
    float v0 = slots[(size_t)row0 * EDIM + t] + a0 + bf;
    float v1 = slots[(size_t)(row0 + 1) * EDIM + t] + a1 + bf;
    if (adjust) {
        const float qq0 = query[(size_t)row0 * EDIM + t];
        const float qq1 = query[(size_t)(row0 + 1) * EDIM + t];
        v0 = (v0 + qq0) - qq0;
        v1 = (v1 + qq1) - qq1;
    }
    q_out[(size_t)row0 * EDIM + t] = v0;
    q_out[(size_t)(row0 + 1) * EDIM + t] = v1;

    if (!do_qpk) return;

    {
        float a0r = v0, q0 = v0 * v0, a1r = v1, q1 = v1 * v1;
#pragma unroll
        for (int m = 1; m < 64; m <<= 1) {
            a0r += __shfl_xor(a0r, m); q0 += __shfl_xor(q0, m);
            a1r += __shfl_xor(a1r, m); q1 += __shfl_xor(q1, m);
        }
        if (lane == 0) { red[wave][0] = a0r; red[wave][1] = q0; red[wave][2] = a1r; red[wave][3] = q1; }
    }
    __syncthreads();
    {
        const float S0 = red[0][0] + red[1][0] + red[2][0] + red[3][0];
        const float Q0 = red[0][1] + red[1][1] + red[2][1] + red[3][1];
        const float S1 = red[0][2] + red[1][2] + red[2][2] + red[3][2];
        const float Q1 = red[0][3] + red[1][3] + red[2][3] + red[3][3];
        const float m0 = S0 * (1.0f / EDIM);
        const float r0 = rsqrtf(Q0 * (1.0f / EDIM) - m0 * m0 + EPS_LN);
        const float m1 = S1 * (1.0f / EDIM);
        const float r1 = rsqrtf(Q1 * (1.0f / EDIM) - m1 * m1 + EPS_LN);
        const float g = g_q[t], bb = b_q[t];
        qn[0][t] = (v0 - m0) * r0 * g + bb;
        qn[1][t] = (v1 - m1) * r1 * g + bb;
    }
    __syncthreads();
    float p0 = 0.f, p1 = 0.f;
#pragma unroll 4
    for (int j = 0; j < EDIM; j += 4) {
        const float4 x0 = *reinterpret_cast<const float4*>(&qn[0][j]);
        const float4 x1 = *reinterpret_cast<const float4*>(&qn[1][j]);
        const float w0 = W[(size_t)j * EDIM + t];
        const float w1 = W[(size_t)(j + 1) * EDIM + t];
        const float w2 = W[(size_t)(j + 2) * EDIM + t];
        const float w3 = W[(size_t)(j + 3) * EDIM + t];
        p0 += x0.x * w0 + x0.y * w1 + x0.z * w2 + x0.w * w3;
        p1 += x1.x * w0 + x1.y * w1 + x1.z * w2 + x1.w * w3;
    }
    qpk[(size_t)row0 * EDIM + t] = p0;
    qpk[(size_t)(row0 + 1) * EDIM + t] = p1;
    {
        const float gk = g_kv[t], bk = b_kv[t];
        float u0 = p0 * gk, w0 = p0 * bk, u1 = p1 * gk, w1 = p1 * bk;
#pragma unroll
        for (int m = 1; m < 64; m <<= 1) {
            u0 += __shfl_xor(u0, m); w0 += __shfl_xor(w0, m);
            u1 += __shfl_xor(u1, m); w1 += __shfl_xor(w1, m);
        }
        __syncthreads();
        if (lane == 0) { red[wave][0] = u0; red[wave][1] = w0; red[wave][2] = u1; red[wave][3] = w1; }
        __syncthreads();
        if (t == 0) {
            const int b = row0 >> 4;
            const int sl = row0 & 15;
            gqbq[b * 32 + sl] = red[0][0] + red[1][0] + red[2][0] + red[3][0];
            gqbq[b * 32 + 16 + sl] = red[0][1] + red[1][1] + red[2][1] + red[3][1];
            gqbq[b * 32 + sl + 1] = red[0][2] + red[1][2] + red[2][2] + red[3][2];
            gqbq[b * 32 + 16 + sl + 1] = red[0][3] + red[1][3] + red[2][3] + red[3][3];
        }
    }
}

extern "C" void kernel_launch(void* const* d_in, const int* in_sizes, int n_in,
                              void* d_out, int out_size, void* d_ws, size_t ws_size,
                              hipStream_t stream) {
    const float* input = (const float*)d_in[0];
    const float* query = (const float*)d_in[1];
    const float* g_kv = (const float*)d_in[2];
    const float* b_kv = (const float*)d_in[3];
    const float* w_k = (const float*)d_in[4];
    const float* w_v = (const float*)d_in[5];
    const float* g_q = (const float*)d_in[6];
    const float* b_q = (const float*)d_in[7];
    const float* w_q = (const float*)d_in[8];
    const float* w_ih = (const float*)d_in[9];
    const float* w_hh = (const float*)d_in[10];
    const float* b_ih = (const float*)d_in[11];
    const float* b_hh = (const float*)d_in[12];
    const float* g_2 = (const float*)d_in[13];
    const float* b_2 = (const float*)d_in[14];
    const float* w_f1 = (const float*)d_in[15];
    const float* b_f1 = (const float*)d_in[16];
    const float* w_f2 = (const float*)d_in[17];
    const float* b_f2 = (const float*)d_in[18];

    float* ws = (float*)d_ws;
    float* W = ws;        ws += 65536;
    float* qpk = ws;      ws += 131072;
    float* gqbq = ws;     ws += 1024;
    float* psum = ws;     ws += 32768;
    float* q_ws = ws;     ws += 131072;
    float* updates = ws;  ws += 131072;
    float* slots = ws;    ws += 131072;
    float* w_vT = ws;     ws += 65536;
    float* w_ihT = ws;    ws += 196608;
    float* w_hhT = ws;    ws += 196608;
    float* w_f1T = ws;    ws += 262144;
    float* w_f2T = ws;    ws += 262144;
    float* pacc = ws;     ws += (size_t)NB * BPB * NS * EDIM;   // 16 MB
    float* gig = pacc;                        // 512*1536 overlay (after k_upd)
    float* h1 = pacc + 786432;                // 512*1024 overlay

    float* out_q = (float*)d_out;
    float* out_attn = out_q + (size_t)NB * NS * EDIM;

    k_prep<<<256, 256, 0, stream>>>(w_q, w_k, W);
    k_tr<<<16, 256, 0, stream>>>(w_v, w_vT, 256, 256);
    k_tr<<<48, 256, 0, stream>>>(w_ih, w_ihT, 768, 256);
    k_tr<<<48, 256, 0, stream>>>(w_hh, w_hhT, 768, 256);
    k_tr<<<64, 256, 0, stream>>>(w_f1, w_f1T, 1024, 256);
    k_tr<<<64, 256, 0, stream>>>(w_f2, w_f2T, 256, 1024);
    k_qproj<<<512, 256, 0, stream>>>(query, g_q, b_q, W, g_kv, b_kv, qpk, gqbq);

    const float* qprev[3] = {query, q_ws, q_ws};
    float* qdst[3] = {q_ws, q_ws, out_q};
    const int adj[3] = {0, 1, 0};

    for (int it = 0; it < 3; ++it) {
        const bool last = (it == 2);
        if (last)
            k_bigpass<true><<<NB * BPB, 256, 0, stream>>>(input, qpk, gqbq, g_kv, pacc, psum, out_attn);
        else
            k_bigpass<false><<<NB * BPB, 256, 0, stream>>>(input, qpk, gqbq, g_kv, pacc, psum, nullptr);
        k_upd<<<256, 256, 0, stream>>>(pacc, psum, g_kv, b_kv, w_vT, updates);
        k_gates<<<768, 256, 0, stream>>>(updates, qprev[it], w_ihT, w_hhT, b_ih, b_hh, gig);
        k_gruffn1<<<512, 256, 0, stream>>>(gig, qprev[it], g_2, b_2, w_f1T, b_f1, slots, h1);
        k_ffn2qpk<<<256, 256, 0, stream>>>(h1, slots, w_f2T, b_f2, query, g_q, b_q, W,
                                           g_kv, b_kv, qdst[it], qpk, gqbq,
                                           adj[it], last ? 0 : 1);
    }
}

// Round 19
// 443.494 us; speedup vs baseline: 2.9698x; 1.0429x over previous
//
#include <hip/hip_runtime.h>
#include <math.h>

#define NB 32
#define HW 4096
#define NS 16
#define EDIM 256
#define FFND 1024
#define EPS_LN 1e-5f
#define EPS_ATTN 1e-5f
#define BPB 32            // sub-blocks per batch in bigpass
#define RPB 128           // rows per bigpass block (HW/BPB)
#define TROWS 16          // rows per barrier-tile

__device__ __forceinline__ float sigmoidf_(float x) { return 1.0f / (1.0f + __expf(-x)); }
__device__ __forceinline__ float gelu_(float x) {
    float x3 = x * x * x;
    return 0.5f * x * (1.0f + tanhf(0.7978845608028654f * (x + 0.044715f * x3)));
}

// Sum across the 16-lane DPP row via row_ror rotations — pure VALU pipe.
__device__ __forceinline__ float rsum16(float v) {
    int x;
    x = __builtin_amdgcn_update_dpp(0, __float_as_int(v), 0x128, 0xF, 0xF, true); // ror:8
    v += __int_as_float(x);
    x = __builtin_amdgcn_update_dpp(0, __float_as_int(v), 0x124, 0xF, 0xF, true); // ror:4
    v += __int_as_float(x);
    x = __builtin_amdgcn_update_dpp(0, __float_as_int(v), 0x122, 0xF, 0xF, true); // ror:2
    v += __int_as_float(x);
    x = __builtin_amdgcn_update_dpp(0, __float_as_int(v), 0x121, 0xF, 0xF, true); // ror:1
    v += __int_as_float(x);
    return v;
}
// Max across the 16-lane DPP row.
__device__ __forceinline__ float rmax16(float v) {
    int x;
    x = __builtin_amdgcn_update_dpp(0, __float_as_int(v), 0x128, 0xF, 0xF, true);
    v = fmaxf(v, __int_as_float(x));
    x = __builtin_amdgcn_update_dpp(0, __float_as_int(v), 0x124, 0xF, 0xF, true);
    v = fmaxf(v, __int_as_float(x));
    x = __builtin_amdgcn_update_dpp(0, __float_as_int(v), 0x122, 0xF, 0xF, true);
    v = fmaxf(v, __int_as_float(x));
    x = __builtin_amdgcn_update_dpp(0, __float_as_int(v), 0x121, 0xF, 0xF, true);
    v = fmaxf(v, __int_as_float(x));
    return v;
}

// W[j][c] = scale * sum_e w_q[e][j] * w_k[e][c]   (scale = 256^-0.5 = 1/16)
__global__ void k_prep(const float* __restrict__ w_q, const float* __restrict__ w_k,
                       float* __restrict__ W) {
    const int j = blockIdx.x;
    const int c = threadIdx.x;
    float acc = 0.f;
    for (int e = 0; e < EDIM; ++e)
        acc += w_q[e * EDIM + j] * w_k[e * EDIM + c];
    W[j * EDIM + c] = acc * 0.0625f;
}

// Tiled transpose: src[R][C] -> dst[C][R].  R,C multiples of 64. 64x64 tiles.
__global__ __launch_bounds__(256) void k_tr(const float* __restrict__ src,
                                            float* __restrict__ dst, int R, int C) {
    __shared__ float tile[64][65];
    const int tilesC = C >> 6;
    const int tR = (blockIdx.x / tilesC) << 6;
    const int tC = (blockIdx.x % tilesC) << 6;
    const int t = threadIdx.x;
    {
        const int r = t >> 2;
        const int c0 = (t & 3) << 4;
#pragma unroll
        for (int i = 0; i < 16; i += 4) {
            const float4 v = *reinterpret_cast<const float4*>(src + (size_t)(tR + r) * C + tC + c0 + i);
            tile[r][c0 + i] = v.x; tile[r][c0 + i + 1] = v.y;
            tile[r][c0 + i + 2] = v.z; tile[r][c0 + i + 3] = v.w;
        }
    }
    __syncthreads();
    {
        const int c = t >> 2;
        const int r0 = (t & 3) << 4;
#pragma unroll
        for (int i = 0; i < 16; ++i)
            dst[(size_t)(tC + c) * R + tR + r0 + i] = tile[r0 + i][c];
    }
}

// Iteration-0 only: qn = LN(query_row); qpk = qn @ W; gq/bq scalars.
__global__ void k_qproj(const float* __restrict__ qsrc, const float* __restrict__ g_q,
                        const float* __restrict__ b_q, const float* __restrict__ W,
                        const float* __restrict__ g_kv, const float* __restrict__ b_kv,
                        float* __restrict__ qpk, float* __restrict__ gqbq) {
    const int row = blockIdx.x;   // 0..511  (= b*16 + s)
    const int t = threadIdx.x;
    __shared__ float qn[EDIM];
    __shared__ float red[16];
    const float v = qsrc[(size_t)row * EDIM + t];
    float s = v, ss = v * v;
#pragma unroll
    for (int m = 1; m < 64; m <<= 1) { s += __shfl_xor(s, m); ss += __shfl_xor(ss, m); }
    const int wave = t >> 6, lane = t & 63;
    if (lane == 0) { red[wave] = s; red[8 + wave] = ss; }
    __syncthreads();
    const float st = red[0] + red[1] + red[2] + red[3];
    const float sst = red[8] + red[9] + red[10] + red[11];
    const float mean = st * (1.0f / EDIM);
    const float rstd = rsqrtf(sst * (1.0f / EDIM) - mean * mean + EPS_LN);
    qn[t] = (v - mean) * rstd * g_q[t] + b_q[t];
    __syncthreads();
    float acc = 0.f;
    for (int j = 0; j < EDIM; ++j)
        acc += qn[j] * W[j * EDIM + t];
    qpk[(size_t)row * EDIM + t] = acc;
    float u = acc * g_kv[t];
    float w2 = acc * b_kv[t];
#pragma unroll
    for (int m = 1; m < 64; m <<= 1) { u += __shfl_xor(u, m); w2 += __shfl_xor(w2, m); }
    __syncthreads();
    if (lane == 0) { red[wave] = u; red[8 + wave] = w2; }
    __syncthreads();
    if (t == 0) {
        const int b = row >> 4, sl = row & 15;
        gqbq[b * 32 + sl] = red[0] + red[1] + red[2] + red[3];
        gqbq[b * 32 + 16 + sl] = red[8] + red[9] + red[10] + red[11];
    }
}

// Streaming pass v10 (unchanged from r18, proven 84us): G in regs, slot-split
// dot, DPP reductions, TROWS=16, register prefetch of next tile.
template <bool LAST>
__global__ __launch_bounds__(256, 2) void k_bigpass(
    const float* __restrict__ input, const float* __restrict__ qpk,
    const float* __restrict__ gqbq, const float* __restrict__ g_kv,
    float* __restrict__ pacc, float* __restrict__ psum, float* __restrict__ attn_out) {
    const int b = blockIdx.x >> 5;        // /BPB
    const int sub = blockIdx.x & 31;      // %BPB
    const int t = threadIdx.x;
    const int w = t >> 6;
    const int lane = t & 63;
    const int gp = (t >> 4) & 3;
    const int g = t >> 4;
    const int j = t & 15;

    __shared__ __align__(16) float stage[TROWS][264];
    __shared__ __align__(16) float wrec[TROWS][20];
    __shared__ __align__(16) float logit_lds[TROWS][NS];

    const float gqj = gqbq[b * 32 + j];
    const float bqj = gqbq[b * 32 + 16 + j];

    float4 Greg[4][4];
#pragma unroll
    for (int sp = 0; sp < 4; ++sp) {
#pragma unroll
        for (int c = 0; c < 4; ++c) {
            const int off = (c * 16 + j) * 4;
            const float4 qv = *reinterpret_cast<const float4*>(
                qpk + (size_t)b * 4096 + (w * 4 + sp) * 256 + off);
            const float4 gv = *reinterpret_cast<const float4*>(g_kv + off);
            Greg[sp][c] = make_float4(qv.x * gv.x, qv.y * gv.y, qv.z * gv.z, qv.w * gv.w);
        }
    }

    float acc[4][4];
    float S[4], A[4];
#pragma unroll
    for (int si = 0; si < 4; ++si) {
        acc[si][0] = acc[si][1] = acc[si][2] = acc[si][3] = 0.f;
        S[si] = 0.f; A[si] = 0.f;
    }

    const int rowbase = sub * RPB;

    float4 xh[4];
    {
        const float* xa = input + ((size_t)b * HW + rowbase + g) * EDIM;
#pragma unroll
        for (int c = 0; c < 4; ++c)
            xh[c] = *reinterpret_cast<const float4*>(xa + (c * 16 + j) * 4);
    }

#pragma unroll 1
    for (int tt = 0; tt < RPB / TROWS; ++tt) {
        const int grow = rowbase + tt * TROWS + g;

        float s1 = 0.f, s2 = 0.f;
#pragma unroll
        for (int c = 0; c < 4; ++c) {
            const int off = (c * 16 + j) * 4;
            *reinterpret_cast<float4*>(&stage[g][off]) = xh[c];
            s1 += xh[c].x + xh[c].y + xh[c].z + xh[c].w;
            s2 += xh[c].x * xh[c].x + xh[c].y * xh[c].y + xh[c].z * xh[c].z + xh[c].w * xh[c].w;
        }
        s1 = rsum16(s1);
        s2 = rsum16(s2);
        const float mean = s1 * (1.0f / EDIM);
        const float rstd = rsqrtf(s2 * (1.0f / EDIM) - mean * mean + EPS_LN);
        __syncthreads();

        if (tt + 1 < RPB / TROWS) {
            const float* xn = input + ((size_t)b * HW + rowbase + (tt + 1) * TROWS + g) * EDIM;
#pragma unroll
            for (int c = 0; c < 4; ++c)
                xh[c] = *reinterpret_cast<const float4*>(xn + (c * 16 + j) * 4);
        }

#pragma unroll
        for (int rb = 0; rb < 4; ++rb) {
            const int row = rb * 4 + gp;
            float d0 = 0.f, d1 = 0.f, d2 = 0.f, d3 = 0.f;
#pragma unroll
            for (int c = 0; c < 4; ++c) {
                const int off = (c * 16 + j) * 4;
                const float4 x = *reinterpret_cast<const float4*>(&stage[row][off]);
                d0 += x.x * Greg[0][c].x + x.y * Greg[0][c].y + x.z * Greg[0][c].z + x.w * Greg[0][c].w;
                d1 += x.x * Greg[1][c].x + x.y * Greg[1][c].y + x.z * Greg[1][c].z + x.w * Greg[1][c].w;
                d2 += x.x * Greg[2][c].x + x.y * Greg[2][c].y + x.z * Greg[2][c].z + x.w * Greg[2][c].w;
                d3 += x.x * Greg[3][c].x + x.y * Greg[3][c].y + x.z * Greg[3][c].z + x.w * Greg[3][c].w;
            }
            d0 = rsum16(d0); d1 = rsum16(d1); d2 = rsum16(d2); d3 = rsum16(d3);
            if (j == 0)
                *reinterpret_cast<float4*>(&logit_lds[row][w * 4]) =
                    make_float4(d0, d1, d2, d3);
        }
        __syncthreads();

        {
            float L = logit_lds[g][j];
            L = rstd * (L - mean * gqj) + bqj;
            const float mx = rmax16(L);
            const float p = __expf(L - mx);
            const float tot = rsum16(p);
            const float at = p / tot;
            wrec[g][j] = at;
            if (j == 0) {
                wrec[g][16] = rstd;
                wrec[g][17] = rstd * mean;
            }
            if (LAST)
                attn_out[((size_t)(b * NS + j)) * HW + grow] = at;
        }
        __syncthreads();

        {
            const int ch = lane * 4;
            const int sbase = w * 4;
#pragma unroll
            for (int r = 0; r < TROWS; ++r) {
                const float4 xv = *reinterpret_cast<const float4*>(&stage[r][ch]);
                const float4 at = *reinterpret_cast<const float4*>(&wrec[r][sbase]);
                const float rr = wrec[r][16];
                const float rm = wrec[r][17];
                float wg;
                wg = at.x * rr;
                acc[0][0] += wg * xv.x; acc[0][1] += wg * xv.y;
                acc[0][2] += wg * xv.z; acc[0][3] += wg * xv.w;
                S[0] += at.x; A[0] += at.x * rm;
                wg = at.y * rr;
                acc[1][0] += wg * xv.x; acc[1][1] += wg * xv.y;
                acc[1][2] += wg * xv.z; acc[1][3] += wg * xv.w;
                S[1] += at.y; A[1] += at.y * rm;
                wg = at.z * rr;
                acc[2][0] += wg * xv.x; acc[2][1] += wg * xv.y;
                acc[2][2] += wg * xv.z; acc[2][3] += wg * xv.w;
                S[2] += at.z; A[2] += at.z * rm;
                wg = at.w * rr;
                acc[3][0] += wg * xv.x; acc[3][1] += wg * xv.y;
                acc[3][2] += wg * xv.z; acc[3][3] += wg * xv.w;
                S[3] += at.w; A[3] += at.w * rm;
            }
        }
        __syncthreads();
    }

#pragma unroll
    for (int si = 0; si < 4; ++si) {
        *reinterpret_cast<float4*>(
            pacc + ((size_t)blockIdx.x * NS + w * 4 + si) * EDIM + lane * 4) =
            make_float4(acc[si][0], acc[si][1], acc[si][2], acc[si][3]);
    }
    if (lane == 0) {
#pragma unroll
        for (int si = 0; si < 4; ++si) {
            psum[blockIdx.x * 32 + w * 4 + si] = S[si];
            psum[blockIdx.x * 32 + 16 + w * 4 + si] = A[si];
        }
    }
}

// G1 v2: 2 rows/block (grid 512 = 2 blk/CU): partial reduce + ub + ub @ w_v.T.
__global__ __launch_bounds__(256) void k_upd(
    const float* __restrict__ pacc, const float* __restrict__ psum,
    const float* __restrict__ g_kv, const float* __restrict__ b_kv,
    const float* __restrict__ w_vT, float* __restrict__ updates) {
    const int rt = blockIdx.x >> 1;      // 0..255, 2 rows each
    const int ct = blockIdx.x & 1;
    const int row0 = rt * 2;
    const int b = row0 >> 4;
    const int s0 = row0 & 15;
    const int t = threadIdx.x;
    __shared__ __align__(16) float ub[2][EDIM];
    __shared__ float sSA[2][2];

    if (t < 4) {
        const int r = t & 1;
        const int isA = t >> 1;
        float v = 0.f;
        for (int p = 0; p < BPB; ++p)
            v += psum[(b * BPB + p) * 32 + isA * 16 + s0 + r];
        sSA[r][isA] = v;
    }
    float V[2];
#pragma unroll
    for (int r = 0; r < 2; ++r) {
        float acc = 0.f;
        for (int p = 0; p < BPB; ++p)
            acc += pacc[((size_t)(b * BPB + p) * NS + s0 + r) * EDIM + t];
        V[r] = acc;
    }
    __syncthreads();
#pragma unroll
    for (int r = 0; r < 2; ++r) {
        const float Sv = sSA[r][0], Av = sSA[r][1];
        ub[r][t] = (g_kv[t] * (V[r] - Av) + b_kv[t] * Sv) / (Sv + EPS_ATTN);
    }
    __syncthreads();

    const int c = ct * 128 + (t & 127);
    const int half = t >> 7;       // row 0/1
    const float* u0 = ub[half];
    float a0 = 0.f;
#pragma unroll 4
    for (int j = 0; j < EDIM; j += 4) {
        const float4 x0 = *reinterpret_cast<const float4*>(u0 + j);
        a0 += x0.x * w_vT[(size_t)j * EDIM + c] + x0.y * w_vT[(size_t)(j + 1) * EDIM + c]
            + x0.z * w_vT[(size_t)(j + 2) * EDIM + c] + x0.w * w_vT[(size_t)(j + 3) * EDIM + c];
    }
    updates[(size_t)(row0 + half) * EDIM + c] = a0;
}

// G2a v2: 2 rows/block (grid 1536 = 6 blk/CU).
__global__ __launch_bounds__(256) void k_gates(
    const float* __restrict__ updates, const float* __restrict__ qprev,
    const float* __restrict__ w_ihT, const float* __restrict__ w_hhT,
    const float* __restrict__ b_ih, const float* __restrict__ b_hh,
    float* __restrict__ gig) {
    const int rt = blockIdx.x / 6;       // 0..255
    const int ct = blockIdx.x % 6;
    const int row0 = rt * 2;
    const int t = threadIdx.x;
    const bool ih = ct < 3;
    const int lc = (ih ? ct : ct - 3) * 256 + t;
    const float* __restrict__ src = ih ? updates : qprev;
    const float* __restrict__ wT = ih ? w_ihT : w_hhT;

    __shared__ __align__(16) float in2[2][EDIM];
#pragma unroll
    for (int r = 0; r < 2; ++r)
        in2[r][t] = src[(size_t)(row0 + r) * EDIM + t];
    __syncthreads();

    float a0 = 0.f, a1 = 0.f;
#pragma unroll 4
    for (int j = 0; j < EDIM; j += 4) {
        const float4 x0 = *reinterpret_cast<const float4*>(&in2[0][j]);
        const float4 x1 = *reinterpret_cast<const float4*>(&in2[1][j]);
        const float w0 = wT[(size_t)j * 768 + lc];
        const float w1 = wT[(size_t)(j + 1) * 768 + lc];
        const float w2 = wT[(size_t)(j + 2) * 768 + lc];
        const float w3 = wT[(size_t)(j + 3) * 768 + lc];
        a0 += x0.x * w0 + x0.y * w1 + x0.z * w2 + x0.w * w3;
        a1 += x1.x * w0 + x1.y * w1 + x1.z * w2 + x1.w * w3;
    }
    const float bias = ih ? b_ih[lc] : b_hh[lc];
    const int gcol = ih ? lc : 768 + lc;
    gig[(size_t)(row0 + 0) * 1536 + gcol] = a0 + bias;
    gig[(size_t)(row0 + 1) * 1536 + gcol] = a1 + bias;
}

// G2b+G3 v2: 2 rows/block (grid 1024 = 4 blk/CU): GRU + LN + ffn1 slice.
__global__ __launch_bounds__(256) void k_gruffn1(
    const float* __restrict__ gig, const float* __restrict__ qprev,
    const float* __restrict__ g_2, const float* __restrict__ b_2,
    const float* __restrict__ w_f1T, const float* __restrict__ b_f1,
    float* __restrict__ slots, float* __restrict__ h1) {
    const int rt = blockIdx.x >> 2;      // 0..255
    const int ct = blockIdx.x & 3;
    const int row0 = rt * 2;
    const int t = threadIdx.x;
    const int wave = t >> 6, lane = t & 63;
    __shared__ __align__(16) float ln2[2][EDIM];
    __shared__ float red[4][4];

    float sl[2];
#pragma unroll
    for (int r = 0; r < 2; ++r) {
        const size_t base = (size_t)(row0 + r) * 1536;
        const float ir = gig[base + t];
        const float iz = gig[base + 256 + t];
        const float inn = gig[base + 512 + t];
        const float hr = gig[base + 768 + t];
        const float hz = gig[base + 1024 + t];
        const float hn = gig[base + 1280 + t];
        const float h = qprev[(size_t)(row0 + r) * EDIM + t];
        const float rg = sigmoidf_(ir + hr);
        const float z = sigmoidf_(iz + hz);
        const float n = tanhf(inn + rg * hn);
        sl[r] = (1.0f - z) * n + z * h;
    }
    if (ct == 0) {
#pragma unroll
        for (int r = 0; r < 2; ++r)
            slots[(size_t)(row0 + r) * EDIM + t] = sl[r];
    }
    {
        float a[2], qq[2];
#pragma unroll
        for (int r = 0; r < 2; ++r) { a[r] = sl[r]; qq[r] = sl[r] * sl[r]; }
#pragma unroll
        for (int m = 1; m < 64; m <<= 1) {
#pragma unroll
            for (int r = 0; r < 2; ++r) {
                a[r] += __shfl_xor(a[r], m);
                qq[r] += __shfl_xor(qq[r], m);
            }
        }
        if (lane == 0) {
#pragma unroll
            for (int r = 0; r < 2; ++r) { red[wave][r] = a[r]; red[wave][2 + r] = qq[r]; }
        }
    }
    __syncthreads();
    {
        const float g = g_2[t], bb = b_2[t];
#pragma unroll
        for (int r = 0; r < 2; ++r) {
            const float Sv = red[0][r] + red[1][r] + red[2][r] + red[3][r];
            const float Qv = red[0][2 + r] + red[1][2 + r] + red[2][2 + r] + red[3][2 + r];
            const float mn = Sv * (1.0f / EDIM);
            const float rs = rsqrtf(Qv * (1.0f / EDIM) - mn * mn + EPS_LN);
            ln2[r][t] = (sl[r] - mn) * rs * g + bb;
        }
    }
    __syncthreads();

    const int c = ct * 256 + t;
    float a0 = 0.f, a1 = 0.f;
#pragma unroll 4
    for (int j = 0; j < EDIM; j += 4) {
        const float4 x0 = *reinterpret_cast<const float4*>(&ln2[0][j]);
        const float4 x1 = *reinterpret_cast<const float4*>(&ln2[1][j]);
        const float w0 = w_f1T[(size_t)j * FFND + c];
        const float w1 = w_f1T[(size_t)(j + 1) * FFND + c];
        const float w2 = w_f1T[(size_t)(j + 2) * FFND + c];
        const float w3 = w_f1T[(size_t)(j + 3) * FFND + c];
        a0 += x0.x * w0 + x0.y * w1 + x0.z * w2 + x0.w * w3;
        a1 += x1.x * w0 + x1.y * w1 + x1.z * w2 + x1.w * w3;
    }
    const float bf = b_f1[c];
    h1[(size_t)(row0 + 0) * FFND + c] = gelu_(a0 + bf);
    h1[(size_t)(row0 + 1) * FFND + c] = gelu_(a1 + bf);
}

// G4+G5 v2: 1 row/block (grid 512 = 2 blk/CU).
__global__ __launch_bounds__(256) void k_ffn2qpk(
    const float* __restrict__ h1, const float* __restrict__ slots,
    const float* __restrict__ w_f2T, const float* __restrict__ b_f2,
    const float* __restrict__ query,
    const float* __restrict__ g_q, const float* __restrict__ b_q,
    const float* __restrict__ W,
    const float* __restrict__ g_kv, const float* __restrict__ b_kv,
    float* __restrict__ q_out, float* __restrict__ qpk, float* __restrict__ gqbq,
    int adjust, int do_qpk) {
    const int row = blockIdx.x;          // 0..511
    const int t = threadIdx.x;
    const int wave = t >> 6, lane = t & 63;
    __shared__ __align__(16) float in1[FFND];
    __shared__ float red[4][2];
    __shared__ __align__(16) float qn[EDIM];

    *reinterpret_cast<float4*>(&in1[t * 4]) =
        *reinterpret_cast<const float4*>(h1 + (size_t)row * FFND + t * 4);
    __syncthreads();
    float a0 = 0.f;
#pragma unroll 4
    for (int j = 0; j < FFND; j += 4) {
        const float4 x0 = *reinterpret_cast<const float4*>(&in1[j]);
        a0 += x0.x * w_f2T[(size_t)j * EDIM + t] + x0.y * w_f2T[(size_t)(j + 1) * EDIM + t]
            + x0.z * w_f2T[(size_t)(j + 2) * EDIM + t] + x0.w * w_f2T[(size_t)(j + 3) * EDIM + t];
    }
    float v0 = slots[(size_t)row * EDIM + t] + a0 + b_f2[t];
    if (adjust) {
        const float qq0 = query[(size_t)row * EDIM + t];
        v0 = (v0 + qq0) - qq0;
    }
    q_out[(size_t)row * EDIM + t] = v0;

    if (!do_qpk) return;

    {
        float s = v0, q0 = v0 * v0;
#pragma unroll
        for (int m = 1; m < 64; m <<= 1) {
            s += __shfl_xor(s, m); q0 += __shfl_xor(q0, m);
        }
        if (lane == 0) { red[wave][0] = s; red[wave][1] = q0; }
    }
    __syncthreads();
    {
        const float S0 = red[0][0] + red[1][0] + red[2][0] + red[3][0];
        const float Q0 = red[0][1] + red[1][1] + red[2][1] + red[3][1];
        const float m0 = S0 * (1.0f / EDIM);
        const float r0 = rsqrtf(Q0 * (1.0f / EDIM) - m0 * m0 + EPS_LN);
        qn[t] = (v0 - m0) * r0 * g_q[t] + b_q[t];
    }
    __syncthreads();
    float p0 = 0.f;
#pragma unroll 4
    for (int j = 0; j < EDIM; j += 4) {
        const float4 x0 = *reinterpret_cast<const float4*>(&qn[j]);
        p0 += x0.x * W[(size_t)j * EDIM + t] + x0.y * W[(size_t)(j + 1) * EDIM + t]
            + x0.z * W[(size_t)(j + 2) * EDIM + t] + x0.w * W[(size_t)(j + 3) * EDIM + t];
    }
    qpk[(size_t)row * EDIM + t] = p0;
    {
        float u0 = p0 * g_kv[t], w0 = p0 * b_kv[t];
#pragma unroll
        for (int m = 1; m < 64; m <<= 1) {
            u0 += __shfl_xor(u0, m); w0 += __shfl_xor(w0, m);
        }
        __syncthreads();
        if (lane == 0) { red[wave][0] = u0; red[wave][1] = w0; }
        __syncthreads();
        if (t == 0) {
            const int b = row >> 4;
            const int sl = row & 15;
            gqbq[b * 32 + sl] = red[0][0] + red[1][0] + red[2][0] + red[3][0];
            gqbq[b * 32 + 16 + sl] = red[0][1] + red[1][1] + red[2][1] + red[3][1];
        }
    }
}

extern "C" void kernel_launch(void* const* d_in, const int* in_sizes, int n_in,
                              void* d_out, int out_size, void* d_ws, size_t ws_size,
                              hipStream_t stream) {
    const float* input = (const float*)d_in[0];
    const float* query = (const float*)d_in[1];
    const float* g_kv = (const float*)d_in[2];
    const float* b_kv = (const float*)d_in[3];
    const float* w_k = (const float*)d_in[4];
    const float* w_v = (const float*)d_in[5];
    const float* g_q = (const float*)d_in[6];
    const float* b_q = (const float*)d_in[7];
    const float* w_q = (const float*)d_in[8];
    const float* w_ih = (const float*)d_in[9];
    const float* w_hh = (const float*)d_in[10];
    const float* b_ih = (const float*)d_in[11];
    const float* b_hh = (const float*)d_in[12];
    const float* g_2 = (const float*)d_in[13];
    const float* b_2 = (const float*)d_in[14];
    const float* w_f1 = (const float*)d_in[15];
    const float* b_f1 = (const float*)d_in[16];
    const float* w_f2 = (const float*)d_in[17];
    const float* b_f2 = (const float*)d_in[18];

    float* ws = (float*)d_ws;
    float* W = ws;        ws += 65536;
    float* qpk = ws;      ws += 131072;
    float* gqbq = ws;     ws += 1024;
    float* psum = ws;     ws += 32768;
    float* q_ws = ws;     ws += 131072;
    float* updates = ws;  ws += 131072;
    float* slots = ws;    ws += 131072;
    float* w_vT = ws;     ws += 65536;
    float* w_ihT = ws;    ws += 196608;
    float* w_hhT = ws;    ws += 196608;
    float* w_f1T = ws;    ws += 262144;
    float* w_f2T = ws;    ws += 262144;
    float* pacc = ws;     ws += (size_t)NB * BPB * NS * EDIM;   // 16 MB
    float* gig = pacc;                        // 512*1536 overlay (after k_upd)
    float* h1 = pacc + 786432;                // 512*1024 overlay

    float* out_q = (float*)d_out;
    float* out_attn = out_q + (size_t)NB * NS * EDIM;

    k_prep<<<256, 256, 0, stream>>>(w_q, w_k, W);
    k_tr<<<16, 256, 0, stream>>>(w_v, w_vT, 256, 256);
    k_tr<<<48, 256, 0, stream>>>(w_ih, w_ihT, 768, 256);
    k_tr<<<48, 256, 0, stream>>>(w_hh, w_hhT, 768, 256);
    k_tr<<<64, 256, 0, stream>>>(w_f1, w_f1T, 1024, 256);
    k_tr<<<64, 256, 0, stream>>>(w_f2, w_f2T, 256, 1024);
    k_qproj<<<512, 256, 0, stream>>>(query, g_q, b_q, W, g_kv, b_kv, qpk, gqbq);

    const float* qprev[3] = {query, q_ws, q_ws};
    float* qdst[3] = {q_ws, q_ws, out_q};
    const int adj[3] = {0, 1, 0};

    for (int it = 0; it < 3; ++it) {
        const bool last = (it == 2);
        if (last)
            k_bigpass<true><<<NB * BPB, 256, 0, stream>>>(input, qpk, gqbq, g_kv, pacc, psum, out_attn);
        else
            k_bigpass<false><<<NB * BPB, 256, 0, stream>>>(input, qpk, gqbq, g_kv, pacc, psum, nullptr);
        k_upd<<<512, 256, 0, stream>>>(pacc, psum, g_kv, b_kv, w_vT, updates);
        k_gates<<<1536, 256, 0, stream>>>(updates, qprev[it], w_ihT, w_hhT, b_ih, b_hh, gig);
        k_gruffn1<<<1024, 256, 0, stream>>>(gig, qprev[it], g_2, b_2, w_f1T, b_f1, slots, h1);
        k_ffn2qpk<<<512, 256, 0, stream>>>(h1, slots, w_f2T, b_f2, query, g_q, b_q, W,
                                           g_kv, b_kv, qdst[it], qpk, gqbq,
                                           adj[it], last ? 0 : 1);
    }
}